// Round 17
// baseline (264.241 us; speedup 1.0000x reference)
//
#include <hip/hip_runtime.h>
#include <hip/hip_bf16.h>
#include <math.h>

#define SEQ 2048
#define BATCH 2
#define TOKENS 4096
#define HEADS 16
#define DHEAD 64
#define TOKSTRIDE 3072

typedef __attribute__((ext_vector_type(4))) float f32x4;
typedef __attribute__((ext_vector_type(16))) float f32x16;
typedef __attribute__((ext_vector_type(8))) __bf16 bf16x8;
typedef __attribute__((ext_vector_type(8))) unsigned short ushort8;
typedef __attribute__((ext_vector_type(4))) unsigned short ushort4_t;
typedef __attribute__((ext_vector_type(4))) unsigned u32x4;
typedef __attribute__((ext_vector_type(2))) unsigned u32x2;

#if __has_builtin(__builtin_amdgcn_exp2f)
#define EXP2(x) __builtin_amdgcn_exp2f(x)
#else
#define EXP2(x) exp2f(x)
#endif

#if __has_builtin(__builtin_amdgcn_permlane32_swap)
#define HAS_PL32 1
#else
#define HAS_PL32 0
#endif

__device__ __forceinline__ unsigned short f2bf(float f) {
  unsigned u = __builtin_bit_cast(unsigned, f);
  u += 0x7fffu + ((u >> 16) & 1u);
  return (unsigned short)(u >> 16);
}

__device__ __forceinline__ float bf2f(unsigned short s) {
  unsigned u = ((unsigned)s) << 16;
  return __builtin_bit_cast(float, u);
}

__device__ __forceinline__ unsigned cvt_pk_bf16(float lo, float hi) {
  unsigned r;
  asm("v_cvt_pk_bf16_f32 %0, %1, %2" : "=v"(r) : "v"(lo), "v"(hi));
  return r;
}

__device__ __forceinline__ void cp16(const void* g, void* l) {
  __builtin_amdgcn_global_load_lds((const __attribute__((address_space(1))) void*)g,
                                   (__attribute__((address_space(3))) void*)l, 16, 0, 0);
}

#define FENCE asm volatile("" ::: "memory")
#define BARR  do { FENCE; __builtin_amdgcn_s_barrier(); FENCE; } while (0)

// ---------------- LayerNorm (1024 cols fixed), fp32 in -> bf16 ----------------
__global__ __launch_bounds__(256) void ln_rows(const float* __restrict__ x,
                                               const float* __restrict__ g,
                                               const float* __restrict__ b,
                                               unsigned short* __restrict__ out) {
  const int row = blockIdx.x;
  const int t = threadIdx.x;
  const f32x4* x4 = (const f32x4*)(x + (size_t)row * 1024);
  f32x4 v = x4[t];
  float sum = v[0] + v[1] + v[2] + v[3];
  float ss  = v[0]*v[0] + v[1]*v[1] + v[2]*v[2] + v[3]*v[3];
#pragma unroll
  for (int off = 1; off < 64; off <<= 1) {
    sum += __shfl_xor(sum, off);
    ss  += __shfl_xor(ss, off);
  }
  __shared__ float red[8];
  const int w = t >> 6, l = t & 63;
  if (l == 0) { red[w] = sum; red[w + 4] = ss; }
  __syncthreads();
  sum = red[0] + red[1] + red[2] + red[3];
  ss  = red[4] + red[5] + red[6] + red[7];
  const float mean = sum * (1.0f / 1024.0f);
  const float var  = ss * (1.0f / 1024.0f) - mean * mean;
  const float rs = rsqrtf(var + 1e-5f);
  ushort4_t o;
#pragma unroll
  for (int j = 0; j < 4; ++j) {
    float gv = g[t * 4 + j], bv = b[t * 4 + j];
    o[j] = f2bf((v[j] - mean) * rs * gv + bv);
  }
  *(ushort4_t*)(out + (size_t)row * 1024 + t * 4) = o;
}

// ---------------- LayerNorm, bf16 in -> bf16 out ----------------
__global__ __launch_bounds__(256) void ln_rows_bf(const unsigned short* __restrict__ x,
                                                  const float* __restrict__ g,
                                                  const float* __restrict__ b,
                                                  unsigned short* __restrict__ out) {
  const int row = blockIdx.x;
  const int t = threadIdx.x;
  ushort4_t v4 = *(const ushort4_t*)(x + (size_t)row * 1024 + t * 4);
  float v[4] = {bf2f(v4[0]), bf2f(v4[1]), bf2f(v4[2]), bf2f(v4[3])};
  float sum = v[0] + v[1] + v[2] + v[3];
  float ss  = v[0]*v[0] + v[1]*v[1] + v[2]*v[2] + v[3]*v[3];
#pragma unroll
  for (int off = 1; off < 64; off <<= 1) {
    sum += __shfl_xor(sum, off);
    ss  += __shfl_xor(ss, off);
  }
  __shared__ float red[8];
  const int w = t >> 6, l = t & 63;
  if (l == 0) { red[w] = sum; red[w + 4] = ss; }
  __syncthreads();
  sum = red[0] + red[1] + red[2] + red[3];
  ss  = red[4] + red[5] + red[6] + red[7];
  const float mean = sum * (1.0f / 1024.0f);
  const float var  = ss * (1.0f / 1024.0f) - mean * mean;
  const float rs = rsqrtf(var + 1e-5f);
  ushort4_t o;
#pragma unroll
  for (int j = 0; j < 4; ++j) {
    float gv = g[t * 4 + j], bv = b[t * 4 + j];
    o[j] = f2bf((v[j] - mean) * rs * gv + bv);
  }
  *(ushort4_t*)(out + (size_t)row * 1024 + t * 4) = o;
}

// ------- merged transpose: all 4 weights in one launch (fp32 [K][N] -> bf16 [N][K]) -------
__global__ __launch_bounds__(256) void transpose_all(
    const float* __restrict__ wqkv, const float* __restrict__ wout,
    const float* __restrict__ w1, const float* __restrict__ w2,
    unsigned short* __restrict__ wqkvT, unsigned short* __restrict__ woutT,
    unsigned short* __restrict__ w1T, unsigned short* __restrict__ w2T) {
  __shared__ float tile[32][33];
  const int bid = blockIdx.x;
  const float* w; unsigned short* wt; int K, N, lb; float scale; int nscaled;
  if (bid < 3072)      { w = wqkv; wt = wqkvT; K = 1024; N = 3072; lb = bid;        scale = 0.18033688f; nscaled = 1024; }
  else if (bid < 4096) { w = wout; wt = woutT; K = 1024; N = 1024; lb = bid - 3072; scale = 1.0f; nscaled = 0; }
  else if (bid < 8192) { w = w1;   wt = w1T;   K = 1024; N = 4096; lb = bid - 4096; scale = 1.0f; nscaled = 0; }
  else                 { w = w2;   wt = w2T;   K = 4096; N = 1024; lb = bid - 8192; scale = 1.0f; nscaled = 0; }
  const int nx = N / 32;
  const int n0 = (lb % nx) * 32, k0 = (lb / nx) * 32;
  const int tx = threadIdx.x & 31;
  const int ty = threadIdx.x >> 5;  // 0..7
#pragma unroll
  for (int i = 0; i < 4; ++i)
    tile[ty + 8 * i][tx] = w[(size_t)(k0 + ty + 8 * i) * N + n0 + tx];
  __syncthreads();
#pragma unroll
  for (int i = 0; i < 4; ++i) {
    int n = n0 + ty + 8 * i;
    float s = (n < nscaled) ? scale : 1.0f;
    wt[(size_t)n * K + k0 + tx] = f2bf(tile[tx][ty + 8 * i] * s);
  }
}

// ---------------- GEMM (R6-proven 2-phase): C[M,N] = A[M,K] * Bt[N,K]^T ----------------
// EPI: 0 = bf16 ; 2 = bf16 gelu(acc+bias) ; 4 = fp32 acc+bias+res_bf16 ;
//      5 = bf16 raw-acc partial (split-K slice ksl)
template <int EPI, int BN, int MINW, int NSPLIT>
__global__ __launch_bounds__(256, MINW) void gemm_bt(
    const unsigned short* __restrict__ A, const unsigned short* __restrict__ Bt,
    void* __restrict__ Cp, const float* __restrict__ bias, const void* __restrict__ resv,
    int M, int N, int K) {
  constexpr int BM = 128, BK = 64;
  constexpr int MR = BM / 32, NR = BN / 32;
  constexpr int AIT = BM * BK / 2048;
  constexpr int BIT = BN * BK / 2048;
  __shared__ unsigned short la[BM * BK];
  __shared__ unsigned short lb[BN * BK];
  const int t = threadIdx.x;
  const int w = t >> 6, l = t & 63;
  const int nwg = gridDim.x;
  const int bid = blockIdx.x;
  const int bid2 = (bid & 7) * (nwg >> 3) + (bid >> 3);  // XCD swizzle (nwg%8==0)
  const int nmn = nwg / NSPLIT;
  const int ksl = bid2 / nmn;
  const int rmn = bid2 - ksl * nmn;
  const int nx = N / BN;
  const int m0 = (rmn / nx) * BM, n0 = (rmn % nx) * BN;
  const int klen = K / NSPLIT;
  const int kbeg = ksl * klen;
  const int wr = w >> 1, wc = w & 1;
  const int lrow = l & 15, lk4 = l >> 4;
  f32x4 acc[MR][NR] = {};

  for (int k0 = kbeg; k0 < kbeg + klen; k0 += BK) {
#pragma unroll
    for (int i = 0; i < AIT; ++i) {
      int idx = t + 256 * i;
      int row = idx >> 3, seg = idx & 7;
      int ss = seg ^ (row & 7);
      cp16(A + (size_t)(m0 + row) * K + k0 + ss * 8, (char*)la + w * 1024 + i * 4096);
    }
#pragma unroll
    for (int i = 0; i < BIT; ++i) {
      int idx = t + 256 * i;
      int row = idx >> 3, seg = idx & 7;
      int ss = seg ^ (row & 7);
      cp16(Bt + (size_t)(n0 + row) * K + k0 + ss * 8, (char*)lb + w * 1024 + i * 4096);
    }
    __syncthreads();
#pragma unroll
    for (int ks = 0; ks < 2; ++ks) {
      bf16x8 af[MR], bfr[NR];
#pragma unroll
      for (int mi = 0; mi < MR; ++mi) {
        int row = wr * (BM / 2) + mi * 16 + lrow;
        int ss = (ks * 4 + lk4) ^ (row & 7);
        af[mi] = *(const bf16x8*)((const char*)la + row * 128 + ss * 16);
      }
#pragma unroll
      for (int ni = 0; ni < NR; ++ni) {
        int row = wc * (BN / 2) + ni * 16 + lrow;
        int ss = (ks * 4 + lk4) ^ (row & 7);
        bfr[ni] = *(const bf16x8*)((const char*)lb + row * 128 + ss * 16);
      }
#pragma unroll
      for (int mi = 0; mi < MR; ++mi)
#pragma unroll
        for (int ni = 0; ni < NR; ++ni)
          acc[mi][ni] = __builtin_amdgcn_mfma_f32_16x16x32_bf16(af[mi], bfr[ni], acc[mi][ni], 0, 0, 0);
    }
    __syncthreads();
  }

#pragma unroll
  for (int mi = 0; mi < MR; ++mi) {
    int rowb = m0 + wr * (BM / 2) + mi * 16 + lk4 * 4;
#pragma unroll
    for (int ni = 0; ni < NR; ++ni) {
      int col = n0 + wc * (BN / 2) + ni * 16 + lrow;
      f32x4 a = acc[mi][ni];
#pragma unroll
      for (int r = 0; r < 4; ++r) {
        size_t off = (size_t)(rowb + r) * N + col;
        if (EPI == 0) {
          ((unsigned short*)Cp)[off] = f2bf(a[r]);
        } else if (EPI == 2) {
          float v = a[r] + bias[col];
          ((unsigned short*)Cp)[off] = f2bf(0.5f * v * (1.0f + erff(v * 0.70710678f)));
        } else if (EPI == 4) {
          ((float*)Cp)[off] = a[r] + bias[col] + bf2f(((const unsigned short*)resv)[off]);
        } else {  // EPI == 5: bf16 partial for split-K
          ((unsigned short*)Cp)[(size_t)ksl * M * N + off] = f2bf(a[r]);
        }
      }
    }
  }
}

// ------ proj GEMM with fused attn-combine on the A operand ------
// A(row,col) = [Σ_c 2^(m_c−M)·Op_c(row,col)] / [Σ_c l_c·2^(m_c−M)], h = col>>6.
// A is reg-staged (global→reg→combine→ds_write_b128, same swizzled layout);
// B stays on cp16. Epilogue: bf16 xa = acc + bias + res_fp32(x).
__global__ __launch_bounds__(256, 3) void proj_fused(
    const unsigned short* __restrict__ Op, const float2* __restrict__ ml,
    const unsigned short* __restrict__ Bt, unsigned short* __restrict__ Cp,
    const float* __restrict__ bias, const float* __restrict__ res,
    int M, int N, int K) {
  constexpr int BM = 128, BN = 64, BK = 64;
  constexpr int MR = 4, NR = 2;
  constexpr int BIT = 2;
  __shared__ unsigned short la[BM * BK];
  __shared__ unsigned short lb[BN * BK];
  const int t = threadIdx.x;
  const int w = t >> 6, l = t & 63;
  const int nwg = gridDim.x;
  const int bid = blockIdx.x;
  const int bid2 = (bid & 7) * (nwg >> 3) + (bid >> 3);
  const int nx = N / BN;
  const int m0 = (bid2 / nx) * BM, n0 = (bid2 % nx) * BN;
  const int wr = w >> 1, wc = w & 1;
  const int lrow = l & 15, lk4 = l >> 4;
  f32x4 acc[MR][NR] = {};

  for (int k0 = 0; k0 < K; k0 += BK) {
    const int h = k0 >> 6;  // one head per K-tile
    // B staging (async)
#pragma unroll
    for (int i = 0; i < BIT; ++i) {
      int idx = t + 256 * i;
      int row = idx >> 3, seg = idx & 7;
      int ss = seg ^ (row & 7);
      cp16(Bt + (size_t)(n0 + row) * K + k0 + ss * 8, (char*)lb + w * 1024 + i * 4096);
    }
    // A staging: load 4 partials + ml, combine, write swizzled
#pragma unroll
    for (int i = 0; i < 4; ++i) {
      int idx = t + 256 * i;
      int row = idx >> 3, seg = idx & 7;
      int grow = m0 + row;
      float2 mm[4];
#pragma unroll
      for (int c = 0; c < 4; ++c) mm[c] = ml[((size_t)c * TOKENS + grow) * 16 + h];
      float Mx = fmaxf(fmaxf(mm[0].x, mm[1].x), fmaxf(mm[2].x, mm[3].x));
      float wgt[4], den = 0.0f;
#pragma unroll
      for (int c = 0; c < 4; ++c) { wgt[c] = EXP2(mm[c].x - Mx); den += mm[c].y * wgt[c]; }
      float inv = 1.0f / den;
      ushort8 op[4];
#pragma unroll
      for (int c = 0; c < 4; ++c)
        op[c] = *(const ushort8*)(Op + ((size_t)c * TOKENS + grow) * 1024 + h * 64 + seg * 8);
      ushort8 o8;
#pragma unroll
      for (int j = 0; j < 8; ++j) {
        float v = wgt[0] * bf2f(op[0][j]) + wgt[1] * bf2f(op[1][j]) +
                  wgt[2] * bf2f(op[2][j]) + wgt[3] * bf2f(op[3][j]);
        o8[j] = f2bf(v * inv);
      }
      *(ushort8*)((char*)la + row * 128 + ((seg ^ (row & 7)) << 4)) = o8;
    }
    __syncthreads();
#pragma unroll
    for (int ks = 0; ks < 2; ++ks) {
      bf16x8 af[MR], bfr[NR];
#pragma unroll
      for (int mi = 0; mi < MR; ++mi) {
        int row = wr * (BM / 2) + mi * 16 + lrow;
        int ss = (ks * 4 + lk4) ^ (row & 7);
        af[mi] = *(const bf16x8*)((const char*)la + row * 128 + ss * 16);
      }
#pragma unroll
      for (int ni = 0; ni < NR; ++ni) {
        int row = wc * (BN / 2) + ni * 16 + lrow;
        int ss = (ks * 4 + lk4) ^ (row & 7);
        bfr[ni] = *(const bf16x8*)((const char*)lb + row * 128 + ss * 16);
      }
#pragma unroll
      for (int mi = 0; mi < MR; ++mi)
#pragma unroll
        for (int ni = 0; ni < NR; ++ni)
          acc[mi][ni] = __builtin_amdgcn_mfma_f32_16x16x32_bf16(af[mi], bfr[ni], acc[mi][ni], 0, 0, 0);
    }
    __syncthreads();
  }

#pragma unroll
  for (int mi = 0; mi < MR; ++mi) {
    int rowb = m0 + wr * (BM / 2) + mi * 16 + lk4 * 4;
#pragma unroll
    for (int ni = 0; ni < NR; ++ni) {
      int col = n0 + wc * (BN / 2) + ni * 16 + lrow;
      f32x4 a = acc[mi][ni];
#pragma unroll
      for (int r = 0; r < 4; ++r) {
        size_t off = (size_t)(rowb + r) * N + col;
        Cp[off] = f2bf(a[r] + bias[col] + res[off]);
      }
    }
  }
}

// ------- split-K(2) combine for MLP2: out = p0 + p1 + b2 + residual(bf16) -------
__global__ __launch_bounds__(256) void mlp2_combine(const unsigned short* __restrict__ p,
                                                    const float* __restrict__ b2,
                                                    const unsigned short* __restrict__ xa,
                                                    float* __restrict__ out) {
  const int row = blockIdx.x, t = threadIdx.x;
  const size_t off = (size_t)row * 1024 + t * 4;
  ushort4_t a = *(const ushort4_t*)(p + off);
  ushort4_t b = *(const ushort4_t*)(p + (size_t)TOKENS * 1024 + off);
  f32x4 bb = *(const f32x4*)(b2 + t * 4);
  ushort4_t xv = *(const ushort4_t*)(xa + off);
  f32x4 o;
#pragma unroll
  for (int j = 0; j < 4; ++j) o[j] = bf2f(a[j]) + bf2f(b[j]) + bb[j] + bf2f(xv[j]);
  *(f32x4*)(out + off) = o;
}

// ---------------- fused flash attention, KV-split x4, single-buffered LDS ----------
// (R14-measured best: 59us; beats double-buffered variant at same split — R15.)
__global__ __launch_bounds__(256, 2) void attn4(const unsigned short* __restrict__ qkv,
                                                unsigned short* __restrict__ Op,
                                                float2* __restrict__ ml) {
  __shared__ unsigned short lk_[64 * 64];  // K [key][d], seg^(key&7) swizzled
  __shared__ unsigned short lvt[64 * 64];  // V^T [d][key], kseg^(d&7) swizzled
  const int t = threadIdx.x, wv = t >> 6, l = t & 63;
  const int chunk = blockIdx.x & 3, qb = blockIdx.x >> 2;
  const int h = blockIdx.y, b = blockIdx.z;
  const size_t tok0 = (size_t)b * SEQ;
  const int lq = l & 31, hi = l >> 5, l7 = l & 7;
  const int qrow = qb * 128 + wv * 32 + lq;
  const int kstart = chunk * 8;

  bf16x8 qf[4];
#pragma unroll
  for (int dc = 0; dc < 4; ++dc)
    qf[dc] = *(const bf16x8*)(qkv + (tok0 + qrow) * TOKSTRIDE + h * DHEAD + dc * 16 + hi * 8);

  float mrun = -1e30f, lsum = 0.0f;
  f32x16 o0 = {}, o1 = {};

  {
#pragma unroll
    for (int i = 0; i < 2; ++i) {
      int idx = t + 256 * i;
      int key = idx >> 3, seg = idx & 7;
      cp16(qkv + (tok0 + kstart * 64 + key) * TOKSTRIDE + 1024 + h * DHEAD + ((seg ^ (key & 7)) << 3),
           (char*)lk_ + wv * 1024 + i * 4096);
    }
#pragma unroll
    for (int i = 0; i < 2; ++i) {
      int idx = t + 256 * i;
      int key = idx & 63, seg = idx >> 6;
      ushort8 v8 = *(const ushort8*)(qkv + (tok0 + kstart * 64 + key) * TOKSTRIDE + 2048 + h * DHEAD + seg * 8);
#pragma unroll
      for (int j = 0; j < 8; ++j) {
        int d = seg * 8 + j;
        lvt[d * 64 + (((key >> 3) ^ (d & 7)) << 3) + (key & 7)] = v8[j];
      }
    }
  }
  __syncthreads();

  for (int kb = 0; kb < 8; ++kb) {
    const bool more = (kb + 1 < 8);
    const int kpre = kstart + kb + 1;

    f32x16 s0 = {}, s1 = {};
    __builtin_amdgcn_s_setprio(1);
#pragma unroll
    for (int dc = 0; dc < 4; ++dc) {
      int sgA = (dc * 2 + hi) ^ l7;
      bf16x8 kf0 = *(const bf16x8*)((const char*)lk_ + lq * 128 + (sgA << 4));
      bf16x8 kf1 = *(const bf16x8*)((const char*)lk_ + (32 + lq) * 128 + (sgA << 4));
      s0 = __builtin_amdgcn_mfma_f32_32x32x16_bf16(kf0, qf[dc], s0, 0, 0, 0);
      s1 = __builtin_amdgcn_mfma_f32_32x32x16_bf16(kf1, qf[dc], s1, 0, 0, 0);
    }
    __builtin_amdgcn_s_setprio(0);

    asm volatile("s_waitcnt lgkmcnt(0)" ::: "memory");
    BARR;
    __builtin_amdgcn_sched_barrier(0);

    ushort8 vpre[2];
    if (more) {
#pragma unroll
      for (int i = 0; i < 2; ++i) {
        int idx = t + 256 * i;
        int key = idx >> 3, seg = idx & 7;
        cp16(qkv + (tok0 + kpre * 64 + key) * TOKSTRIDE + 1024 + h * DHEAD + ((seg ^ (key & 7)) << 3),
             (char*)lk_ + wv * 1024 + i * 4096);
      }
#pragma unroll
      for (int i = 0; i < 2; ++i) {
        int idx = t + 256 * i;
        int key = idx & 63, seg = idx >> 6;
        vpre[i] = *(const ushort8*)(qkv + (tok0 + kpre * 64 + key) * TOKSTRIDE + 2048 + h * DHEAD + seg * 8);
      }
    }

    float mx[8];
#pragma unroll
    for (int r = 0; r < 8; ++r)
      mx[r] = fmaxf(fmaxf(s0[r], s0[r + 8]), fmaxf(s1[r], s1[r + 8]));
#pragma unroll
    for (int r = 0; r < 4; ++r) mx[r] = fmaxf(mx[r], mx[r + 4]);
    float m01 = fmaxf(fmaxf(mx[0], mx[1]), fmaxf(mx[2], mx[3]));
    float pm = fmaxf(m01, __shfl_xor(m01, 32));

    if (__any(pm > mrun + 8.0f)) {
      float mn = fmaxf(mrun, pm);
      float alpha = EXP2(mrun - mn);
      mrun = mn;
      lsum *= alpha;
#pragma unroll
      for (int r = 0; r < 16; ++r) {
        int qi = (r & 3) + 8 * (r >> 2) + 4 * hi;
        float ar = __shfl(alpha, qi);
        o0[r] *= ar; o1[r] *= ar;
      }
    }

    float p0[16], p1[16], ts[16];
#pragma unroll
    for (int r = 0; r < 16; ++r) { p0[r] = EXP2(s0[r] - mrun); }
#pragma unroll
    for (int r = 0; r < 16; ++r) { p1[r] = EXP2(s1[r] - mrun); }
#pragma unroll
    for (int r = 0; r < 16; ++r) ts[r] = p0[r] + p1[r];
#pragma unroll
    for (int st = 8; st > 0; st >>= 1)
#pragma unroll
      for (int r = 0; r < 8; ++r)
        if (r < st) ts[r] += ts[r + st];
    float psum = ts[0] + __shfl_xor(ts[0], 32);
    lsum += psum;

    unsigned W0[8], W1[8];
#pragma unroll
    for (int mI = 0; mI < 8; ++mI) {
      W0[mI] = cvt_pk_bf16(p0[2 * mI], p0[2 * mI + 1]);
      W1[mI] = cvt_pk_bf16(p1[2 * mI], p1[2 * mI + 1]);
    }
#if !HAS_PL32
    unsigned X0[8], X1[8];
#pragma unroll
    for (int mI = 0; mI < 8; ++mI) {
      X0[mI] = __shfl_xor((int)W0[mI], 32);
      X1[mI] = __shfl_xor((int)W1[mI], 32);
    }
#endif

    __builtin_amdgcn_s_setprio(1);
#pragma unroll
    for (int kt = 0; kt < 2; ++kt) {
#pragma unroll
      for (int c = 0; c < 2; ++c) {
        u32x4 fw;
#if HAS_PL32
        unsigned a0 = (kt == 0) ? W0[4 * c + 0] : W1[4 * c + 0];
        unsigned a1 = (kt == 0) ? W0[4 * c + 1] : W1[4 * c + 1];
        unsigned b0 = (kt == 0) ? W0[4 * c + 2] : W1[4 * c + 2];
        unsigned b1 = (kt == 0) ? W0[4 * c + 3] : W1[4 * c + 3];
        u32x2 pa = __builtin_amdgcn_permlane32_swap(a0, b0, false, false);
        u32x2 pb = __builtin_amdgcn_permlane32_swap(a1, b1, false, false);
        fw[0] = pa[0]; fw[1] = pb[0]; fw[2] = pa[1]; fw[3] = pb[1];
#else
        if (kt == 0) {
          fw[0] = hi ? X0[4 * c + 2] : W0[4 * c + 0];
          fw[1] = hi ? X0[4 * c + 3] : W0[4 * c + 1];
          fw[2] = hi ? W0[4 * c + 2] : X0[4 * c + 0];
          fw[3] = hi ? W0[4 * c + 3] : X0[4 * c + 1];
        } else {
          fw[0] = hi ? X1[4 * c + 2] : W1[4 * c + 0];
          fw[1] = hi ? X1[4 * c + 3] : W1[4 * c + 1];
          fw[2] = hi ? W1[4 * c + 2] : X1[4 * c + 0];
          fw[3] = hi ? W1[4 * c + 3] : X1[4 * c + 1];
        }
#endif
        bf16x8 pf = __builtin_bit_cast(bf16x8, fw);
        int ksg = (kt * 4 + c * 2 + hi) ^ l7;
        bf16x8 vfA = *(const bf16x8*)((const char*)lvt + lq * 128 + (ksg << 4));
        bf16x8 vfB = *(const bf16x8*)((const char*)lvt + (32 + lq) * 128 + (ksg << 4));
        o0 = __builtin_amdgcn_mfma_f32_32x32x16_bf16(pf, vfA, o0, 0, 0, 0);
        o1 = __builtin_amdgcn_mfma_f32_32x32x16_bf16(pf, vfB, o1, 0, 0, 0);
      }
    }
    __builtin_amdgcn_s_setprio(0);

    asm volatile("s_waitcnt lgkmcnt(0)" ::: "memory");
    BARR;
    __builtin_amdgcn_sched_barrier(0);

    if (more) {
#pragma unroll
      for (int i = 0; i < 2; ++i) {
        int idx = t + 256 * i;
        int key = idx & 63, seg = idx >> 6;
#pragma unroll
        for (int j = 0; j < 8; ++j) {
          int d = seg * 8 + j;
          lvt[d * 64 + (((key >> 3) ^ (d & 7)) << 3) + (key & 7)] = vpre[i][j];
        }
      }
    }
    asm volatile("s_waitcnt vmcnt(0) lgkmcnt(0)" ::: "memory");
    BARR;
    __builtin_amdgcn_sched_barrier(0);
  }

  const size_t cbase = (size_t)chunk * TOKENS;
#pragma unroll
  for (int r = 0; r < 16; ++r) {
    int qi = (r & 3) + 8 * (r >> 2) + 4 * hi;
    size_t rowoff = (cbase + tok0 + qb * 128 + wv * 32 + qi) * (size_t)1024 + h * DHEAD;
    Op[rowoff + lq]      = f2bf(o0[r]);
    Op[rowoff + 32 + lq] = f2bf(o1[r]);
  }
  if (l < 32) {
    size_t tokr = tok0 + qb * 128 + wv * 32 + lq;
    ml[(cbase + tokr) * 16 + h] = make_float2(mrun, lsum);
  }
}

extern "C" void kernel_launch(void* const* d_in, const int* in_sizes, int n_in,
                              void* d_out, int out_size, void* d_ws, size_t ws_size,
                              hipStream_t stream) {
  const float* x    = (const float*)d_in[0];
  const float* ln1g = (const float*)d_in[1];
  const float* ln1b = (const float*)d_in[2];
  const float* wqkv = (const float*)d_in[3];
  const float* wout = (const float*)d_in[4];
  const float* bout = (const float*)d_in[5];
  const float* ln2g = (const float*)d_in[6];
  const float* ln2b = (const float*)d_in[7];
  const float* w1   = (const float*)d_in[8];
  const float* b1   = (const float*)d_in[9];
  const float* w2   = (const float*)d_in[10];
  const float* b2   = (const float*)d_in[11];

  char* ws = (char*)d_ws;
  unsigned short* wqkvT = (unsigned short*)ws; ws += (size_t)3072 * 1024 * 2;
  unsigned short* woutT = (unsigned short*)ws; ws += (size_t)1024 * 1024 * 2;
  unsigned short* w1T   = (unsigned short*)ws; ws += (size_t)4096 * 1024 * 2;
  unsigned short* w2T   = (unsigned short*)ws; ws += (size_t)1024 * 4096 * 2;
  unsigned short* h1    = (unsigned short*)ws; ws += (size_t)TOKENS * 1024 * 2;
  unsigned short* qkvb  = (unsigned short*)ws; ws += (size_t)TOKENS * 3072 * 2;
  unsigned short* attno = (unsigned short*)ws; ws += (size_t)TOKENS * 1024 * 2;  // (unused; kept for layout)
  unsigned short* xa    = (unsigned short*)ws; ws += (size_t)TOKENS * 1024 * 4;  // bf16 (slot fp32-sized)
  unsigned short* h2    = (unsigned short*)ws; ws += (size_t)TOKENS * 1024 * 2;
  unsigned short* hid   = (unsigned short*)ws; ws += (size_t)TOKENS * 4096 * 2;
  float2*         mlbuf = (float2*)ws;         ws += (size_t)4 * TOKENS * 16 * 8;
  unsigned short* Opart = hid;  // alias: 4x bf16 partials = 32MB = hid, dead until MLP1
  unsigned short* mlp2p = h1;   // alias: 2x bf16 partials = 16MB in h1+qkvb; dead after attn4

  // 0.125 (attn scale) * log2(e) folded into W_q -> softmax in 2^x domain
  transpose_all<<<12288, 256, 0, stream>>>(wqkv, wout, w1, w2, wqkvT, woutT, w1T, w2T);

  ln_rows<<<TOKENS, 256, 0, stream>>>(x, ln1g, ln1b, h1);
  gemm_bt<0, 128, 2, 1><<<768, 256, 0, stream>>>(h1, wqkvT, qkvb, nullptr, nullptr, TOKENS, 3072, 1024);
  attn4<<<dim3(4 * SEQ / 128, HEADS, BATCH), 256, 0, stream>>>(qkvb, Opart, mlbuf);
  // proj with fused flash-decode combine on the A operand
  proj_fused<<<512, 256, 0, stream>>>(Opart, mlbuf, woutT, xa, bout, x, TOKENS, 1024, 1024);
  ln_rows_bf<<<TOKENS, 256, 0, stream>>>(xa, ln2g, ln2b, h2);
  gemm_bt<2, 128, 2, 1><<<1024, 256, 0, stream>>>(h2, w1T, hid, b1, nullptr, TOKENS, 4096, 1024);
  // MLP2 split-K x2, BN=128, bf16 partials
  gemm_bt<5, 128, 2, 2><<<512, 256, 0, stream>>>(hid, w2T, mlp2p, nullptr, nullptr, TOKENS, 1024, 4096);
  mlp2_combine<<<TOKENS, 256, 0, stream>>>(mlp2p, b2, xa, (float*)d_out);
}

// Round 18
// 234.104 us; speedup vs baseline: 1.1287x; 1.1287x over previous
//
#include <hip/hip_runtime.h>
#include <hip/hip_bf16.h>
#include <math.h>

#define SEQ 2048
#define BATCH 2
#define TOKENS 4096
#define HEADS 16
#define DHEAD 64
#define TOKSTRIDE 3072

typedef __attribute__((ext_vector_type(4))) float f32x4;
typedef __attribute__((ext_vector_type(16))) float f32x16;
typedef __attribute__((ext_vector_type(8))) __bf16 bf16x8;
typedef __attribute__((ext_vector_type(8))) unsigned short ushort8;
typedef __attribute__((ext_vector_type(4))) unsigned short ushort4_t;
typedef __attribute__((ext_vector_type(4))) unsigned u32x4;
typedef __attribute__((ext_vector_type(2))) unsigned u32x2;

#if __has_builtin(__builtin_amdgcn_exp2f)
#define EXP2(x) __builtin_amdgcn_exp2f(x)
#else
#define EXP2(x) exp2f(x)
#endif

#if __has_builtin(__builtin_amdgcn_permlane32_swap)
#define HAS_PL32 1
#else
#define HAS_PL32 0
#endif

__device__ __forceinline__ unsigned short f2bf(float f) {
  unsigned u = __builtin_bit_cast(unsigned, f);
  u += 0x7fffu + ((u >> 16) & 1u);
  return (unsigned short)(u >> 16);
}

__device__ __forceinline__ float bf2f(unsigned short s) {
  unsigned u = ((unsigned)s) << 16;
  return __builtin_bit_cast(float, u);
}

__device__ __forceinline__ unsigned cvt_pk_bf16(float lo, float hi) {
  unsigned r;
  asm("v_cvt_pk_bf16_f32 %0, %1, %2" : "=v"(r) : "v"(lo), "v"(hi));
  return r;
}

__device__ __forceinline__ void cp16(const void* g, void* l) {
  __builtin_amdgcn_global_load_lds((const __attribute__((address_space(1))) void*)g,
                                   (__attribute__((address_space(3))) void*)l, 16, 0, 0);
}

#define FENCE asm volatile("" ::: "memory")
#define BARR  do { FENCE; __builtin_amdgcn_s_barrier(); FENCE; } while (0)

// ---------------- LayerNorm (1024 cols fixed), fp32 in -> bf16 ----------------
__global__ __launch_bounds__(256) void ln_rows(const float* __restrict__ x,
                                               const float* __restrict__ g,
                                               const float* __restrict__ b,
                                               unsigned short* __restrict__ out) {
  const int row = blockIdx.x;
  const int t = threadIdx.x;
  const f32x4* x4 = (const f32x4*)(x + (size_t)row * 1024);
  f32x4 v = x4[t];
  float sum = v[0] + v[1] + v[2] + v[3];
  float ss  = v[0]*v[0] + v[1]*v[1] + v[2]*v[2] + v[3]*v[3];
#pragma unroll
  for (int off = 1; off < 64; off <<= 1) {
    sum += __shfl_xor(sum, off);
    ss  += __shfl_xor(ss, off);
  }
  __shared__ float red[8];
  const int w = t >> 6, l = t & 63;
  if (l == 0) { red[w] = sum; red[w + 4] = ss; }
  __syncthreads();
  sum = red[0] + red[1] + red[2] + red[3];
  ss  = red[4] + red[5] + red[6] + red[7];
  const float mean = sum * (1.0f / 1024.0f);
  const float var  = ss * (1.0f / 1024.0f) - mean * mean;
  const float rs = rsqrtf(var + 1e-5f);
  ushort4_t o;
#pragma unroll
  for (int j = 0; j < 4; ++j) {
    float gv = g[t * 4 + j], bv = b[t * 4 + j];
    o[j] = f2bf((v[j] - mean) * rs * gv + bv);
  }
  *(ushort4_t*)(out + (size_t)row * 1024 + t * 4) = o;
}

// ---------------- LayerNorm, bf16 in -> bf16 out ----------------
__global__ __launch_bounds__(256) void ln_rows_bf(const unsigned short* __restrict__ x,
                                                  const float* __restrict__ g,
                                                  const float* __restrict__ b,
                                                  unsigned short* __restrict__ out) {
  const int row = blockIdx.x;
  const int t = threadIdx.x;
  ushort4_t v4 = *(const ushort4_t*)(x + (size_t)row * 1024 + t * 4);
  float v[4] = {bf2f(v4[0]), bf2f(v4[1]), bf2f(v4[2]), bf2f(v4[3])};
  float sum = v[0] + v[1] + v[2] + v[3];
  float ss  = v[0]*v[0] + v[1]*v[1] + v[2]*v[2] + v[3]*v[3];
#pragma unroll
  for (int off = 1; off < 64; off <<= 1) {
    sum += __shfl_xor(sum, off);
    ss  += __shfl_xor(ss, off);
  }
  __shared__ float red[8];
  const int w = t >> 6, l = t & 63;
  if (l == 0) { red[w] = sum; red[w + 4] = ss; }
  __syncthreads();
  sum = red[0] + red[1] + red[2] + red[3];
  ss  = red[4] + red[5] + red[6] + red[7];
  const float mean = sum * (1.0f / 1024.0f);
  const float var  = ss * (1.0f / 1024.0f) - mean * mean;
  const float rs = rsqrtf(var + 1e-5f);
  ushort4_t o;
#pragma unroll
  for (int j = 0; j < 4; ++j) {
    float gv = g[t * 4 + j], bv = b[t * 4 + j];
    o[j] = f2bf((v[j] - mean) * rs * gv + bv);
  }
  *(ushort4_t*)(out + (size_t)row * 1024 + t * 4) = o;
}

// ------- merged transpose: all 4 weights in one launch (fp32 [K][N] -> bf16 [N][K]) -------
__global__ __launch_bounds__(256) void transpose_all(
    const float* __restrict__ wqkv, const float* __restrict__ wout,
    const float* __restrict__ w1, const float* __restrict__ w2,
    unsigned short* __restrict__ wqkvT, unsigned short* __restrict__ woutT,
    unsigned short* __restrict__ w1T, unsigned short* __restrict__ w2T) {
  __shared__ float tile[32][33];
  const int bid = blockIdx.x;
  const float* w; unsigned short* wt; int K, N, lb; float scale; int nscaled;
  if (bid < 3072)      { w = wqkv; wt = wqkvT; K = 1024; N = 3072; lb = bid;        scale = 0.18033688f; nscaled = 1024; }
  else if (bid < 4096) { w = wout; wt = woutT; K = 1024; N = 1024; lb = bid - 3072; scale = 1.0f; nscaled = 0; }
  else if (bid < 8192) { w = w1;   wt = w1T;   K = 1024; N = 4096; lb = bid - 4096; scale = 1.0f; nscaled = 0; }
  else                 { w = w2;   wt = w2T;   K = 4096; N = 1024; lb = bid - 8192; scale = 1.0f; nscaled = 0; }
  const int nx = N / 32;
  const int n0 = (lb % nx) * 32, k0 = (lb / nx) * 32;
  const int tx = threadIdx.x & 31;
  const int ty = threadIdx.x >> 5;  // 0..7
#pragma unroll
  for (int i = 0; i < 4; ++i)
    tile[ty + 8 * i][tx] = w[(size_t)(k0 + ty + 8 * i) * N + n0 + tx];
  __syncthreads();
#pragma unroll
  for (int i = 0; i < 4; ++i) {
    int n = n0 + ty + 8 * i;
    float s = (n < nscaled) ? scale : 1.0f;
    wt[(size_t)n * K + k0 + tx] = f2bf(tile[tx][ty + 8 * i] * s);
  }
}

// ---------------- GEMM (R6-proven 2-phase): C[M,N] = A[M,K] * Bt[N,K]^T ----------------
// EPI: 0 = bf16 ; 2 = bf16 gelu(acc+bias) ; 3 = bf16 acc+bias+res_fp32 ;
//      4 = fp32 acc+bias+res_bf16 ; 5 = bf16 raw-acc partial (split-K slice ksl)
template <int EPI, int BN, int MINW, int NSPLIT>
__global__ __launch_bounds__(256, MINW) void gemm_bt(
    const unsigned short* __restrict__ A, const unsigned short* __restrict__ Bt,
    void* __restrict__ Cp, const float* __restrict__ bias, const void* __restrict__ resv,
    int M, int N, int K) {
  constexpr int BM = 128, BK = 64;
  constexpr int MR = BM / 32, NR = BN / 32;
  constexpr int AIT = BM * BK / 2048;
  constexpr int BIT = BN * BK / 2048;
  __shared__ unsigned short la[BM * BK];
  __shared__ unsigned short lb[BN * BK];
  const int t = threadIdx.x;
  const int w = t >> 6, l = t & 63;
  const int nwg = gridDim.x;
  const int bid = blockIdx.x;
  const int bid2 = (bid & 7) * (nwg >> 3) + (bid >> 3);  // XCD swizzle (nwg%8==0)
  const int nmn = nwg / NSPLIT;
  const int ksl = bid2 / nmn;
  const int rmn = bid2 - ksl * nmn;
  const int nx = N / BN;
  const int m0 = (rmn / nx) * BM, n0 = (rmn % nx) * BN;
  const int klen = K / NSPLIT;
  const int kbeg = ksl * klen;
  const int wr = w >> 1, wc = w & 1;
  const int lrow = l & 15, lk4 = l >> 4;
  f32x4 acc[MR][NR] = {};

  for (int k0 = kbeg; k0 < kbeg + klen; k0 += BK) {
#pragma unroll
    for (int i = 0; i < AIT; ++i) {
      int idx = t + 256 * i;
      int row = idx >> 3, seg = idx & 7;
      int ss = seg ^ (row & 7);
      cp16(A + (size_t)(m0 + row) * K + k0 + ss * 8, (char*)la + w * 1024 + i * 4096);
    }
#pragma unroll
    for (int i = 0; i < BIT; ++i) {
      int idx = t + 256 * i;
      int row = idx >> 3, seg = idx & 7;
      int ss = seg ^ (row & 7);
      cp16(Bt + (size_t)(n0 + row) * K + k0 + ss * 8, (char*)lb + w * 1024 + i * 4096);
    }
    __syncthreads();
#pragma unroll
    for (int ks = 0; ks < 2; ++ks) {
      bf16x8 af[MR], bfr[NR];
#pragma unroll
      for (int mi = 0; mi < MR; ++mi) {
        int row = wr * (BM / 2) + mi * 16 + lrow;
        int ss = (ks * 4 + lk4) ^ (row & 7);
        af[mi] = *(const bf16x8*)((const char*)la + row * 128 + ss * 16);
      }
#pragma unroll
      for (int ni = 0; ni < NR; ++ni) {
        int row = wc * (BN / 2) + ni * 16 + lrow;
        int ss = (ks * 4 + lk4) ^ (row & 7);
        bfr[ni] = *(const bf16x8*)((const char*)lb + row * 128 + ss * 16);
      }
#pragma unroll
      for (int mi = 0; mi < MR; ++mi)
#pragma unroll
        for (int ni = 0; ni < NR; ++ni)
          acc[mi][ni] = __builtin_amdgcn_mfma_f32_16x16x32_bf16(af[mi], bfr[ni], acc[mi][ni], 0, 0, 0);
    }
    __syncthreads();
  }

#pragma unroll
  for (int mi = 0; mi < MR; ++mi) {
    int rowb = m0 + wr * (BM / 2) + mi * 16 + lk4 * 4;
#pragma unroll
    for (int ni = 0; ni < NR; ++ni) {
      int col = n0 + wc * (BN / 2) + ni * 16 + lrow;
      f32x4 a = acc[mi][ni];
#pragma unroll
      for (int r = 0; r < 4; ++r) {
        size_t off = (size_t)(rowb + r) * N + col;
        if (EPI == 0) {
          ((unsigned short*)Cp)[off] = f2bf(a[r]);
        } else if (EPI == 2) {
          float v = a[r] + bias[col];
          ((unsigned short*)Cp)[off] = f2bf(0.5f * v * (1.0f + erff(v * 0.70710678f)));
        } else if (EPI == 3) {
          ((unsigned short*)Cp)[off] = f2bf(a[r] + bias[col] + ((const float*)resv)[off]);
        } else if (EPI == 4) {
          ((float*)Cp)[off] = a[r] + bias[col] + bf2f(((const unsigned short*)resv)[off]);
        } else {  // EPI == 5: bf16 partial for split-K
          ((unsigned short*)Cp)[(size_t)ksl * M * N + off] = f2bf(a[r]);
        }
      }
    }
  }
}

// ------- split-K(2) combine for MLP2: out = p0 + p1 + b2 + residual(bf16) -------
__global__ __launch_bounds__(256) void mlp2_combine(const unsigned short* __restrict__ p,
                                                    const float* __restrict__ b2,
                                                    const unsigned short* __restrict__ xa,
                                                    float* __restrict__ out) {
  const int row = blockIdx.x, t = threadIdx.x;
  const size_t off = (size_t)row * 1024 + t * 4;
  ushort4_t a = *(const ushort4_t*)(p + off);
  ushort4_t b = *(const ushort4_t*)(p + (size_t)TOKENS * 1024 + off);
  f32x4 bb = *(const f32x4*)(b2 + t * 4);
  ushort4_t xv = *(const ushort4_t*)(xa + off);
  f32x4 o;
#pragma unroll
  for (int j = 0; j < 4; ++j) o[j] = bf2f(a[j]) + bf2f(b[j]) + bb[j] + bf2f(xv[j]);
  *(f32x4*)(out + off) = o;
}

// ---------------- fused flash attention, KV-split x4, single-buffered LDS ----------
// (R14-measured best: 59us; beats double-buffered variant at same split — R15.)
__global__ __launch_bounds__(256, 2) void attn4(const unsigned short* __restrict__ qkv,
                                                unsigned short* __restrict__ Op,
                                                float2* __restrict__ ml) {
  __shared__ unsigned short lk_[64 * 64];  // K [key][d], seg^(key&7) swizzled
  __shared__ unsigned short lvt[64 * 64];  // V^T [d][key], kseg^(d&7) swizzled
  const int t = threadIdx.x, wv = t >> 6, l = t & 63;
  const int chunk = blockIdx.x & 3, qb = blockIdx.x >> 2;
  const int h = blockIdx.y, b = blockIdx.z;
  const size_t tok0 = (size_t)b * SEQ;
  const int lq = l & 31, hi = l >> 5, l7 = l & 7;
  const int qrow = qb * 128 + wv * 32 + lq;
  const int kstart = chunk * 8;

  bf16x8 qf[4];
#pragma unroll
  for (int dc = 0; dc < 4; ++dc)
    qf[dc] = *(const bf16x8*)(qkv + (tok0 + qrow) * TOKSTRIDE + h * DHEAD + dc * 16 + hi * 8);

  float mrun = -1e30f, lsum = 0.0f;
  f32x16 o0 = {}, o1 = {};

  {
#pragma unroll
    for (int i = 0; i < 2; ++i) {
      int idx = t + 256 * i;
      int key = idx >> 3, seg = idx & 7;
      cp16(qkv + (tok0 + kstart * 64 + key) * TOKSTRIDE + 1024 + h * DHEAD + ((seg ^ (key & 7)) << 3),
           (char*)lk_ + wv * 1024 + i * 4096);
    }
#pragma unroll
    for (int i = 0; i < 2; ++i) {
      int idx = t + 256 * i;
      int key = idx & 63, seg = idx >> 6;
      ushort8 v8 = *(const ushort8*)(qkv + (tok0 + kstart * 64 + key) * TOKSTRIDE + 2048 + h * DHEAD + seg * 8);
#pragma unroll
      for (int j = 0; j < 8; ++j) {
        int d = seg * 8 + j;
        lvt[d * 64 + (((key >> 3) ^ (d & 7)) << 3) + (key & 7)] = v8[j];
      }
    }
  }
  __syncthreads();

  for (int kb = 0; kb < 8; ++kb) {
    const bool more = (kb + 1 < 8);
    const int kpre = kstart + kb + 1;

    f32x16 s0 = {}, s1 = {};
    __builtin_amdgcn_s_setprio(1);
#pragma unroll
    for (int dc = 0; dc < 4; ++dc) {
      int sgA = (dc * 2 + hi) ^ l7;
      bf16x8 kf0 = *(const bf16x8*)((const char*)lk_ + lq * 128 + (sgA << 4));
      bf16x8 kf1 = *(const bf16x8*)((const char*)lk_ + (32 + lq) * 128 + (sgA << 4));
      s0 = __builtin_amdgcn_mfma_f32_32x32x16_bf16(kf0, qf[dc], s0, 0, 0, 0);
      s1 = __builtin_amdgcn_mfma_f32_32x32x16_bf16(kf1, qf[dc], s1, 0, 0, 0);
    }
    __builtin_amdgcn_s_setprio(0);

    asm volatile("s_waitcnt lgkmcnt(0)" ::: "memory");
    BARR;
    __builtin_amdgcn_sched_barrier(0);

    ushort8 vpre[2];
    if (more) {
#pragma unroll
      for (int i = 0; i < 2; ++i) {
        int idx = t + 256 * i;
        int key = idx >> 3, seg = idx & 7;
        cp16(qkv + (tok0 + kpre * 64 + key) * TOKSTRIDE + 1024 + h * DHEAD + ((seg ^ (key & 7)) << 3),
             (char*)lk_ + wv * 1024 + i * 4096);
      }
#pragma unroll
      for (int i = 0; i < 2; ++i) {
        int idx = t + 256 * i;
        int key = idx & 63, seg = idx >> 6;
        vpre[i] = *(const ushort8*)(qkv + (tok0 + kpre * 64 + key) * TOKSTRIDE + 2048 + h * DHEAD + seg * 8);
      }
    }

    float mx[8];
#pragma unroll
    for (int r = 0; r < 8; ++r)
      mx[r] = fmaxf(fmaxf(s0[r], s0[r + 8]), fmaxf(s1[r], s1[r + 8]));
#pragma unroll
    for (int r = 0; r < 4; ++r) mx[r] = fmaxf(mx[r], mx[r + 4]);
    float m01 = fmaxf(fmaxf(mx[0], mx[1]), fmaxf(mx[2], mx[3]));
    float pm = fmaxf(m01, __shfl_xor(m01, 32));

    if (__any(pm > mrun + 8.0f)) {
      float mn = fmaxf(mrun, pm);
      float alpha = EXP2(mrun - mn);
      mrun = mn;
      lsum *= alpha;
#pragma unroll
      for (int r = 0; r < 16; ++r) {
        int qi = (r & 3) + 8 * (r >> 2) + 4 * hi;
        float ar = __shfl(alpha, qi);
        o0[r] *= ar; o1[r] *= ar;
      }
    }

    float p0[16], p1[16], ts[16];
#pragma unroll
    for (int r = 0; r < 16; ++r) { p0[r] = EXP2(s0[r] - mrun); }
#pragma unroll
    for (int r = 0; r < 16; ++r) { p1[r] = EXP2(s1[r] - mrun); }
#pragma unroll
    for (int r = 0; r < 16; ++r) ts[r] = p0[r] + p1[r];
#pragma unroll
    for (int st = 8; st > 0; st >>= 1)
#pragma unroll
      for (int r = 0; r < 8; ++r)
        if (r < st) ts[r] += ts[r + st];
    float psum = ts[0] + __shfl_xor(ts[0], 32);
    lsum += psum;

    unsigned W0[8], W1[8];
#pragma unroll
    for (int mI = 0; mI < 8; ++mI) {
      W0[mI] = cvt_pk_bf16(p0[2 * mI], p0[2 * mI + 1]);
      W1[mI] = cvt_pk_bf16(p1[2 * mI], p1[2 * mI + 1]);
    }
#if !HAS_PL32
    unsigned X0[8], X1[8];
#pragma unroll
    for (int mI = 0; mI < 8; ++mI) {
      X0[mI] = __shfl_xor((int)W0[mI], 32);
      X1[mI] = __shfl_xor((int)W1[mI], 32);
    }
#endif

    __builtin_amdgcn_s_setprio(1);
#pragma unroll
    for (int kt = 0; kt < 2; ++kt) {
#pragma unroll
      for (int c = 0; c < 2; ++c) {
        u32x4 fw;
#if HAS_PL32
        unsigned a0 = (kt == 0) ? W0[4 * c + 0] : W1[4 * c + 0];
        unsigned a1 = (kt == 0) ? W0[4 * c + 1] : W1[4 * c + 1];
        unsigned b0 = (kt == 0) ? W0[4 * c + 2] : W1[4 * c + 2];
        unsigned b1 = (kt == 0) ? W0[4 * c + 3] : W1[4 * c + 3];
        u32x2 pa = __builtin_amdgcn_permlane32_swap(a0, b0, false, false);
        u32x2 pb = __builtin_amdgcn_permlane32_swap(a1, b1, false, false);
        fw[0] = pa[0]; fw[1] = pb[0]; fw[2] = pa[1]; fw[3] = pb[1];
#else
        if (kt == 0) {
          fw[0] = hi ? X0[4 * c + 2] : W0[4 * c + 0];
          fw[1] = hi ? X0[4 * c + 3] : W0[4 * c + 1];
          fw[2] = hi ? W0[4 * c + 2] : X0[4 * c + 0];
          fw[3] = hi ? W0[4 * c + 3] : X0[4 * c + 1];
        } else {
          fw[0] = hi ? X1[4 * c + 2] : W1[4 * c + 0];
          fw[1] = hi ? X1[4 * c + 3] : W1[4 * c + 1];
          fw[2] = hi ? W1[4 * c + 2] : X1[4 * c + 0];
          fw[3] = hi ? W1[4 * c + 3] : X1[4 * c + 1];
        }
#endif
        bf16x8 pf = __builtin_bit_cast(bf16x8, fw);
        int ksg = (kt * 4 + c * 2 + hi) ^ l7;
        bf16x8 vfA = *(const bf16x8*)((const char*)lvt + lq * 128 + (ksg << 4));
        bf16x8 vfB = *(const bf16x8*)((const char*)lvt + (32 + lq) * 128 + (ksg << 4));
        o0 = __builtin_amdgcn_mfma_f32_32x32x16_bf16(pf, vfA, o0, 0, 0, 0);
        o1 = __builtin_amdgcn_mfma_f32_32x32x16_bf16(pf, vfB, o1, 0, 0, 0);
      }
    }
    __builtin_amdgcn_s_setprio(0);

    asm volatile("s_waitcnt lgkmcnt(0)" ::: "memory");
    BARR;
    __builtin_amdgcn_sched_barrier(0);

    if (more) {
#pragma unroll
      for (int i = 0; i < 2; ++i) {
        int idx = t + 256 * i;
        int key = idx & 63, seg = idx >> 6;
#pragma unroll
        for (int j = 0; j < 8; ++j) {
          int d = seg * 8 + j;
          lvt[d * 64 + (((key >> 3) ^ (d & 7)) << 3) + (key & 7)] = vpre[i][j];
        }
      }
    }
    asm volatile("s_waitcnt vmcnt(0) lgkmcnt(0)" ::: "memory");
    BARR;
    __builtin_amdgcn_sched_barrier(0);
  }

  const size_t cbase = (size_t)chunk * TOKENS;
#pragma unroll
  for (int r = 0; r < 16; ++r) {
    int qi = (r & 3) + 8 * (r >> 2) + 4 * hi;
    size_t rowoff = (cbase + tok0 + qb * 128 + wv * 32 + qi) * (size_t)1024 + h * DHEAD;
    Op[rowoff + lq]      = f2bf(o0[r]);
    Op[rowoff + 32 + lq] = f2bf(o1[r]);
  }
  if (l < 32) {
    size_t tokr = tok0 + qb * 128 + wv * 32 + lq;
    ml[(cbase + tokr) * 16 + h] = make_float2(mrun, lsum);
  }
}

// ---------------- combine the 4 KV-chunk partials -> bf16 attno ----------------
__global__ __launch_bounds__(256) void attn_combine4(const unsigned short* __restrict__ Op,
                                                     const float2* __restrict__ ml,
                                                     unsigned short* __restrict__ out) {
  const int t = threadIdx.x, w = t >> 6, l = t & 63;
  const size_t tok = blockIdx.x * 4 + w;
#pragma unroll
  for (int h = 0; h < 16; ++h) {
    float2 mm[4];
#pragma unroll
    for (int c = 0; c < 4; ++c) mm[c] = ml[((size_t)c * TOKENS + tok) * 16 + h];
    float M = fmaxf(fmaxf(mm[0].x, mm[1].x), fmaxf(mm[2].x, mm[3].x));
    float wgt[4];
    float den = 0.0f;
#pragma unroll
    for (int c = 0; c < 4; ++c) { wgt[c] = EXP2(mm[c].x - M); den += mm[c].y * wgt[c]; }
    float inv = 1.0f / den;
    int col = h * 64 + l;
    float o = 0.0f;
#pragma unroll
    for (int c = 0; c < 4; ++c)
      o += bf2f(Op[((size_t)c * TOKENS + tok) * 1024 + col]) * wgt[c];
    out[tok * 1024 + col] = f2bf(o * inv);
  }
}

extern "C" void kernel_launch(void* const* d_in, const int* in_sizes, int n_in,
                              void* d_out, int out_size, void* d_ws, size_t ws_size,
                              hipStream_t stream) {
  const float* x    = (const float*)d_in[0];
  const float* ln1g = (const float*)d_in[1];
  const float* ln1b = (const float*)d_in[2];
  const float* wqkv = (const float*)d_in[3];
  const float* wout = (const float*)d_in[4];
  const float* bout = (const float*)d_in[5];
  const float* ln2g = (const float*)d_in[6];
  const float* ln2b = (const float*)d_in[7];
  const float* w1   = (const float*)d_in[8];
  const float* b1   = (const float*)d_in[9];
  const float* w2   = (const float*)d_in[10];
  const float* b2   = (const float*)d_in[11];

  char* ws = (char*)d_ws;
  unsigned short* wqkvT = (unsigned short*)ws; ws += (size_t)3072 * 1024 * 2;
  unsigned short* woutT = (unsigned short*)ws; ws += (size_t)1024 * 1024 * 2;
  unsigned short* w1T   = (unsigned short*)ws; ws += (size_t)4096 * 1024 * 2;
  unsigned short* w2T   = (unsigned short*)ws; ws += (size_t)1024 * 4096 * 2;
  unsigned short* h1    = (unsigned short*)ws; ws += (size_t)TOKENS * 1024 * 2;
  unsigned short* qkvb  = (unsigned short*)ws; ws += (size_t)TOKENS * 3072 * 2;
  unsigned short* attno = (unsigned short*)ws; ws += (size_t)TOKENS * 1024 * 2;
  unsigned short* xa    = (unsigned short*)ws; ws += (size_t)TOKENS * 1024 * 4;  // bf16 (slot fp32-sized)
  unsigned short* h2    = (unsigned short*)ws; ws += (size_t)TOKENS * 1024 * 2;
  unsigned short* hid   = (unsigned short*)ws; ws += (size_t)TOKENS * 4096 * 2;
  float2*         mlbuf = (float2*)ws;         ws += (size_t)4 * TOKENS * 16 * 8;
  unsigned short* Opart = hid;  // alias: 4x bf16 partials = 32MB = hid, dead until MLP1
  unsigned short* mlp2p = h1;   // alias: 2x bf16 partials = 16MB in h1+qkvb; dead after attn4

  // 0.125 (attn scale) * log2(e) folded into W_q -> softmax in 2^x domain
  transpose_all<<<12288, 256, 0, stream>>>(wqkv, wout, w1, w2, wqkvT, woutT, w1T, w2T);

  ln_rows<<<TOKENS, 256, 0, stream>>>(x, ln1g, ln1b, h1);
  gemm_bt<0, 128, 2, 1><<<768, 256, 0, stream>>>(h1, wqkvT, qkvb, nullptr, nullptr, TOKENS, 3072, 1024);
  attn4<<<dim3(4 * SEQ / 128, HEADS, BATCH), 256, 0, stream>>>(qkvb, Opart, mlbuf);
  attn_combine4<<<TOKENS / 4, 256, 0, stream>>>(Opart, mlbuf, attno);
  gemm_bt<3, 64, 3, 1><<<512, 256, 0, stream>>>(attno, woutT, xa, bout, x, TOKENS, 1024, 1024);
  ln_rows_bf<<<TOKENS, 256, 0, stream>>>(xa, ln2g, ln2b, h2);
  gemm_bt<2, 128, 2, 1><<<1024, 256, 0, stream>>>(h2, w1T, hid, b1, nullptr, TOKENS, 4096, 1024);
  // MLP2 split-K x2, BN=128, bf16 partials
  gemm_bt<5, 128, 2, 2><<<512, 256, 0, stream>>>(hid, w2T, mlp2p, nullptr, nullptr, TOKENS, 1024, 4096);
  mlp2_combine<<<TOKENS, 256, 0, stream>>>(mlp2p, b2, xa, (float*)d_out);
}

// Round 19
// 233.408 us; speedup vs baseline: 1.1321x; 1.0030x over previous
//
#include <hip/hip_runtime.h>
#include <hip/hip_bf16.h>
#include <math.h>

#define SEQ 2048
#define BATCH 2
#define TOKENS 4096
#define HEADS 16
#define DHEAD 64
#define TOKSTRIDE 3072

typedef __attribute__((ext_vector_type(4))) float f32x4;
typedef __attribute__((ext_vector_type(16))) float f32x16;
typedef __attribute__((ext_vector_type(8))) __bf16 bf16x8;
typedef __attribute__((ext_vector_type(8))) unsigned short ushort8;
typedef __attribute__((ext_vector_type(4))) unsigned short ushort4_t;
typedef __attribute__((ext_vector_type(4))) unsigned u32x4;
typedef __attribute__((ext_vector_type(2))) unsigned u32x2;

#if __has_builtin(__builtin_amdgcn_exp2f)
#define EXP2(x) __builtin_amdgcn_exp2f(x)
#else
#define EXP2(x) exp2f(x)
#endif

#if __has_builtin(__builtin_amdgcn_permlane32_swap)
#define HAS_PL32 1
#else
#define HAS_PL32 0
#endif

__device__ __forceinline__ unsigned short f2bf(float f) {
  unsigned u = __builtin_bit_cast(unsigned, f);
  u += 0x7fffu + ((u >> 16) & 1u);
  return (unsigned short)(u >> 16);
}

__device__ __forceinline__ float bf2f(unsigned short s) {
  unsigned u = ((unsigned)s) << 16;
  return __builtin_bit_cast(float, u);
}

__device__ __forceinline__ unsigned cvt_pk_bf16(float lo, float hi) {
  unsigned r;
  asm("v_cvt_pk_bf16_f32 %0, %1, %2" : "=v"(r) : "v"(lo), "v"(hi));
  return r;
}

__device__ __forceinline__ void cp16(const void* g, void* l) {
  __builtin_amdgcn_global_load_lds((const __attribute__((address_space(1))) void*)g,
                                   (__attribute__((address_space(3))) void*)l, 16, 0, 0);
}

#define FENCE asm volatile("" ::: "memory")
#define BARR  do { FENCE; __builtin_amdgcn_s_barrier(); FENCE; } while (0)

// ---------------- LayerNorm (1024 cols fixed), fp32 in -> bf16 ----------------
__global__ __launch_bounds__(256) void ln_rows(const float* __restrict__ x,
                                               const float* __restrict__ g,
                                               const float* __restrict__ b,
                                               unsigned short* __restrict__ out) {
  const int row = blockIdx.x;
  const int t = threadIdx.x;
  const f32x4* x4 = (const f32x4*)(x + (size_t)row * 1024);
  f32x4 v = x4[t];
  float sum = v[0] + v[1] + v[2] + v[3];
  float ss  = v[0]*v[0] + v[1]*v[1] + v[2]*v[2] + v[3]*v[3];
#pragma unroll
  for (int off = 1; off < 64; off <<= 1) {
    sum += __shfl_xor(sum, off);
    ss  += __shfl_xor(ss, off);
  }
  __shared__ float red[8];
  const int w = t >> 6, l = t & 63;
  if (l == 0) { red[w] = sum; red[w + 4] = ss; }
  __syncthreads();
  sum = red[0] + red[1] + red[2] + red[3];
  ss  = red[4] + red[5] + red[6] + red[7];
  const float mean = sum * (1.0f / 1024.0f);
  const float var  = ss * (1.0f / 1024.0f) - mean * mean;
  const float rs = rsqrtf(var + 1e-5f);
  ushort4_t o;
#pragma unroll
  for (int j = 0; j < 4; ++j) {
    float gv = g[t * 4 + j], bv = b[t * 4 + j];
    o[j] = f2bf((v[j] - mean) * rs * gv + bv);
  }
  *(ushort4_t*)(out + (size_t)row * 1024 + t * 4) = o;
}

// ---------------- LayerNorm, bf16 in -> bf16 out ----------------
__global__ __launch_bounds__(256) void ln_rows_bf(const unsigned short* __restrict__ x,
                                                  const float* __restrict__ g,
                                                  const float* __restrict__ b,
                                                  unsigned short* __restrict__ out) {
  const int row = blockIdx.x;
  const int t = threadIdx.x;
  ushort4_t v4 = *(const ushort4_t*)(x + (size_t)row * 1024 + t * 4);
  float v[4] = {bf2f(v4[0]), bf2f(v4[1]), bf2f(v4[2]), bf2f(v4[3])};
  float sum = v[0] + v[1] + v[2] + v[3];
  float ss  = v[0]*v[0] + v[1]*v[1] + v[2]*v[2] + v[3]*v[3];
#pragma unroll
  for (int off = 1; off < 64; off <<= 1) {
    sum += __shfl_xor(sum, off);
    ss  += __shfl_xor(ss, off);
  }
  __shared__ float red[8];
  const int w = t >> 6, l = t & 63;
  if (l == 0) { red[w] = sum; red[w + 4] = ss; }
  __syncthreads();
  sum = red[0] + red[1] + red[2] + red[3];
  ss  = red[4] + red[5] + red[6] + red[7];
  const float mean = sum * (1.0f / 1024.0f);
  const float var  = ss * (1.0f / 1024.0f) - mean * mean;
  const float rs = rsqrtf(var + 1e-5f);
  ushort4_t o;
#pragma unroll
  for (int j = 0; j < 4; ++j) {
    float gv = g[t * 4 + j], bv = b[t * 4 + j];
    o[j] = f2bf((v[j] - mean) * rs * gv + bv);
  }
  *(ushort4_t*)(out + (size_t)row * 1024 + t * 4) = o;
}

// ------- merged transpose: all 4 weights in one launch (fp32 [K][N] -> bf16 [N][K]) -------
__global__ __launch_bounds__(256) void transpose_all(
    const float* __restrict__ wqkv, const float* __restrict__ wout,
    const float* __restrict__ w1, const float* __restrict__ w2,
    unsigned short* __restrict__ wqkvT, unsigned short* __restrict__ woutT,
    unsigned short* __restrict__ w1T, unsigned short* __restrict__ w2T) {
  __shared__ float tile[32][33];
  const int bid = blockIdx.x;
  const float* w; unsigned short* wt; int K, N, lb; float scale; int nscaled;
  if (bid < 3072)      { w = wqkv; wt = wqkvT; K = 1024; N = 3072; lb = bid;        scale = 0.18033688f; nscaled = 1024; }
  else if (bid < 4096) { w = wout; wt = woutT; K = 1024; N = 1024; lb = bid - 3072; scale = 1.0f; nscaled = 0; }
  else if (bid < 8192) { w = w1;   wt = w1T;   K = 1024; N = 4096; lb = bid - 4096; scale = 1.0f; nscaled = 0; }
  else                 { w = w2;   wt = w2T;   K = 4096; N = 1024; lb = bid - 8192; scale = 1.0f; nscaled = 0; }
  const int nx = N / 32;
  const int n0 = (lb % nx) * 32, k0 = (lb / nx) * 32;
  const int tx = threadIdx.x & 31;
  const int ty = threadIdx.x >> 5;  // 0..7
#pragma unroll
  for (int i = 0; i < 4; ++i)
    tile[ty + 8 * i][tx] = w[(size_t)(k0 + ty + 8 * i) * N + n0 + tx];
  __syncthreads();
#pragma unroll
  for (int i = 0; i < 4; ++i) {
    int n = n0 + ty + 8 * i;
    float s = (n < nscaled) ? scale : 1.0f;
    wt[(size_t)n * K + k0 + tx] = f2bf(tile[tx][ty + 8 * i] * s);
  }
}

// ---------------- GEMM (R6-proven 2-phase): C[M,N] = A[M,K] * Bt[N,K]^T ----------------
// EPI: 0 = bf16 ; 2 = bf16 gelu(acc+bias) ; 3 = bf16 acc+bias+res_fp32 ;
//      4 = fp32 acc+bias+res_bf16 ; 5 = bf16 raw-acc partial (split-K slice ksl)
template <int EPI, int BN, int MINW, int NSPLIT>
__global__ __launch_bounds__(256, MINW) void gemm_bt(
    const unsigned short* __restrict__ A, const unsigned short* __restrict__ Bt,
    void* __restrict__ Cp, const float* __restrict__ bias, const void* __restrict__ resv,
    int M, int N, int K) {
  constexpr int BM = 128, BK = 64;
  constexpr int MR = BM / 32, NR = BN / 32;
  constexpr int AIT = BM * BK / 2048;
  constexpr int BIT = BN * BK / 2048;
  __shared__ unsigned short la[BM * BK];
  __shared__ unsigned short lb[BN * BK];
  const int t = threadIdx.x;
  const int w = t >> 6, l = t & 63;
  const int nwg = gridDim.x;
  const int bid = blockIdx.x;
  const int bid2 = (bid & 7) * (nwg >> 3) + (bid >> 3);  // XCD swizzle (nwg%8==0)
  const int nmn = nwg / NSPLIT;
  const int ksl = bid2 / nmn;
  const int rmn = bid2 - ksl * nmn;
  const int nx = N / BN;
  const int m0 = (rmn / nx) * BM, n0 = (rmn % nx) * BN;
  const int klen = K / NSPLIT;
  const int kbeg = ksl * klen;
  const int wr = w >> 1, wc = w & 1;
  const int lrow = l & 15, lk4 = l >> 4;
  f32x4 acc[MR][NR] = {};

  for (int k0 = kbeg; k0 < kbeg + klen; k0 += BK) {
#pragma unroll
    for (int i = 0; i < AIT; ++i) {
      int idx = t + 256 * i;
      int row = idx >> 3, seg = idx & 7;
      int ss = seg ^ (row & 7);
      cp16(A + (size_t)(m0 + row) * K + k0 + ss * 8, (char*)la + w * 1024 + i * 4096);
    }
#pragma unroll
    for (int i = 0; i < BIT; ++i) {
      int idx = t + 256 * i;
      int row = idx >> 3, seg = idx & 7;
      int ss = seg ^ (row & 7);
      cp16(Bt + (size_t)(n0 + row) * K + k0 + ss * 8, (char*)lb + w * 1024 + i * 4096);
    }
    __syncthreads();
#pragma unroll
    for (int ks = 0; ks < 2; ++ks) {
      bf16x8 af[MR], bfr[NR];
#pragma unroll
      for (int mi = 0; mi < MR; ++mi) {
        int row = wr * (BM / 2) + mi * 16 + lrow;
        int ss = (ks * 4 + lk4) ^ (row & 7);
        af[mi] = *(const bf16x8*)((const char*)la + row * 128 + ss * 16);
      }
#pragma unroll
      for (int ni = 0; ni < NR; ++ni) {
        int row = wc * (BN / 2) + ni * 16 + lrow;
        int ss = (ks * 4 + lk4) ^ (row & 7);
        bfr[ni] = *(const bf16x8*)((const char*)lb + row * 128 + ss * 16);
      }
#pragma unroll
      for (int mi = 0; mi < MR; ++mi)
#pragma unroll
        for (int ni = 0; ni < NR; ++ni)
          acc[mi][ni] = __builtin_amdgcn_mfma_f32_16x16x32_bf16(af[mi], bfr[ni], acc[mi][ni], 0, 0, 0);
    }
    __syncthreads();
  }

#pragma unroll
  for (int mi = 0; mi < MR; ++mi) {
    int rowb = m0 + wr * (BM / 2) + mi * 16 + lk4 * 4;
#pragma unroll
    for (int ni = 0; ni < NR; ++ni) {
      int col = n0 + wc * (BN / 2) + ni * 16 + lrow;
      f32x4 a = acc[mi][ni];
#pragma unroll
      for (int r = 0; r < 4; ++r) {
        size_t off = (size_t)(rowb + r) * N + col;
        if (EPI == 0) {
          ((unsigned short*)Cp)[off] = f2bf(a[r]);
        } else if (EPI == 2) {
          float v = a[r] + bias[col];
          ((unsigned short*)Cp)[off] = f2bf(0.5f * v * (1.0f + erff(v * 0.70710678f)));
        } else if (EPI == 3) {
          ((unsigned short*)Cp)[off] = f2bf(a[r] + bias[col] + ((const float*)resv)[off]);
        } else if (EPI == 4) {
          ((float*)Cp)[off] = a[r] + bias[col] + bf2f(((const unsigned short*)resv)[off]);
        } else {  // EPI == 5: bf16 partial for split-K
          ((unsigned short*)Cp)[(size_t)ksl * M * N + off] = f2bf(a[r]);
        }
      }
    }
  }
}

// ------- split-K(2) combine for MLP2: out = p0 + p1 + b2 + residual(bf16) -------
__global__ __launch_bounds__(256) void mlp2_combine(const unsigned short* __restrict__ p,
                                                    const float* __restrict__ b2,
                                                    const unsigned short* __restrict__ xa,
                                                    float* __restrict__ out) {
  const int row = blockIdx.x, t = threadIdx.x;
  const size_t off = (size_t)row * 1024 + t * 4;
  ushort4_t a = *(const ushort4_t*)(p + off);
  ushort4_t b = *(const ushort4_t*)(p + (size_t)TOKENS * 1024 + off);
  f32x4 bb = *(const f32x4*)(b2 + t * 4);
  ushort4_t xv = *(const ushort4_t*)(xa + off);
  f32x4 o;
#pragma unroll
  for (int j = 0; j < 4; ++j) o[j] = bf2f(a[j]) + bf2f(b[j]) + bb[j] + bf2f(xv[j]);
  *(f32x4*)(out + off) = o;
}

// ---------------- fused flash attention, KV-split x2, single-buffered LDS ----------
// Single-buffer body is the measured best (R14 vs R15: -10us vs dbuf). Split x2
// halves the partial-combine traffic vs x4 (split factor itself was ~neutral).
__global__ __launch_bounds__(256, 2) void attn4(const unsigned short* __restrict__ qkv,
                                                unsigned short* __restrict__ Op,
                                                float2* __restrict__ ml) {
  __shared__ unsigned short lk_[64 * 64];  // K [key][d], seg^(key&7) swizzled
  __shared__ unsigned short lvt[64 * 64];  // V^T [d][key], kseg^(d&7) swizzled
  const int t = threadIdx.x, wv = t >> 6, l = t & 63;
  const int chunk = blockIdx.x & 1, qb = blockIdx.x >> 1;
  const int h = blockIdx.y, b = blockIdx.z;
  const size_t tok0 = (size_t)b * SEQ;
  const int lq = l & 31, hi = l >> 5, l7 = l & 7;
  const int qrow = qb * 128 + wv * 32 + lq;
  const int kstart = chunk * 16;  // 16 tiles of 64 keys per chunk

  bf16x8 qf[4];
#pragma unroll
  for (int dc = 0; dc < 4; ++dc)
    qf[dc] = *(const bf16x8*)(qkv + (tok0 + qrow) * TOKSTRIDE + h * DHEAD + dc * 16 + hi * 8);

  float mrun = -1e30f, lsum = 0.0f;
  f32x16 o0 = {}, o1 = {};

  {
#pragma unroll
    for (int i = 0; i < 2; ++i) {
      int idx = t + 256 * i;
      int key = idx >> 3, seg = idx & 7;
      cp16(qkv + (tok0 + kstart * 64 + key) * TOKSTRIDE + 1024 + h * DHEAD + ((seg ^ (key & 7)) << 3),
           (char*)lk_ + wv * 1024 + i * 4096);
    }
#pragma unroll
    for (int i = 0; i < 2; ++i) {
      int idx = t + 256 * i;
      int key = idx & 63, seg = idx >> 6;
      ushort8 v8 = *(const ushort8*)(qkv + (tok0 + kstart * 64 + key) * TOKSTRIDE + 2048 + h * DHEAD + seg * 8);
#pragma unroll
      for (int j = 0; j < 8; ++j) {
        int d = seg * 8 + j;
        lvt[d * 64 + (((key >> 3) ^ (d & 7)) << 3) + (key & 7)] = v8[j];
      }
    }
  }
  __syncthreads();

  for (int kb = 0; kb < 16; ++kb) {
    const bool more = (kb + 1 < 16);
    const int kpre = kstart + kb + 1;

    f32x16 s0 = {}, s1 = {};
    __builtin_amdgcn_s_setprio(1);
#pragma unroll
    for (int dc = 0; dc < 4; ++dc) {
      int sgA = (dc * 2 + hi) ^ l7;
      bf16x8 kf0 = *(const bf16x8*)((const char*)lk_ + lq * 128 + (sgA << 4));
      bf16x8 kf1 = *(const bf16x8*)((const char*)lk_ + (32 + lq) * 128 + (sgA << 4));
      s0 = __builtin_amdgcn_mfma_f32_32x32x16_bf16(kf0, qf[dc], s0, 0, 0, 0);
      s1 = __builtin_amdgcn_mfma_f32_32x32x16_bf16(kf1, qf[dc], s1, 0, 0, 0);
    }
    __builtin_amdgcn_s_setprio(0);

    asm volatile("s_waitcnt lgkmcnt(0)" ::: "memory");
    BARR;
    __builtin_amdgcn_sched_barrier(0);

    ushort8 vpre[2];
    if (more) {
#pragma unroll
      for (int i = 0; i < 2; ++i) {
        int idx = t + 256 * i;
        int key = idx >> 3, seg = idx & 7;
        cp16(qkv + (tok0 + kpre * 64 + key) * TOKSTRIDE + 1024 + h * DHEAD + ((seg ^ (key & 7)) << 3),
             (char*)lk_ + wv * 1024 + i * 4096);
      }
#pragma unroll
      for (int i = 0; i < 2; ++i) {
        int idx = t + 256 * i;
        int key = idx & 63, seg = idx >> 6;
        vpre[i] = *(const ushort8*)(qkv + (tok0 + kpre * 64 + key) * TOKSTRIDE + 2048 + h * DHEAD + seg * 8);
      }
    }

    float mx[8];
#pragma unroll
    for (int r = 0; r < 8; ++r)
      mx[r] = fmaxf(fmaxf(s0[r], s0[r + 8]), fmaxf(s1[r], s1[r + 8]));
#pragma unroll
    for (int r = 0; r < 4; ++r) mx[r] = fmaxf(mx[r], mx[r + 4]);
    float m01 = fmaxf(fmaxf(mx[0], mx[1]), fmaxf(mx[2], mx[3]));
    float pm = fmaxf(m01, __shfl_xor(m01, 32));

    if (__any(pm > mrun + 8.0f)) {
      float mn = fmaxf(mrun, pm);
      float alpha = EXP2(mrun - mn);
      mrun = mn;
      lsum *= alpha;
#pragma unroll
      for (int r = 0; r < 16; ++r) {
        int qi = (r & 3) + 8 * (r >> 2) + 4 * hi;
        float ar = __shfl(alpha, qi);
        o0[r] *= ar; o1[r] *= ar;
      }
    }

    float p0[16], p1[16], ts[16];
#pragma unroll
    for (int r = 0; r < 16; ++r) { p0[r] = EXP2(s0[r] - mrun); }
#pragma unroll
    for (int r = 0; r < 16; ++r) { p1[r] = EXP2(s1[r] - mrun); }
#pragma unroll
    for (int r = 0; r < 16; ++r) ts[r] = p0[r] + p1[r];
#pragma unroll
    for (int st = 8; st > 0; st >>= 1)
#pragma unroll
      for (int r = 0; r < 8; ++r)
        if (r < st) ts[r] += ts[r + st];
    float psum = ts[0] + __shfl_xor(ts[0], 32);
    lsum += psum;

    unsigned W0[8], W1[8];
#pragma unroll
    for (int mI = 0; mI < 8; ++mI) {
      W0[mI] = cvt_pk_bf16(p0[2 * mI], p0[2 * mI + 1]);
      W1[mI] = cvt_pk_bf16(p1[2 * mI], p1[2 * mI + 1]);
    }
#if !HAS_PL32
    unsigned X0[8], X1[8];
#pragma unroll
    for (int mI = 0; mI < 8; ++mI) {
      X0[mI] = __shfl_xor((int)W0[mI], 32);
      X1[mI] = __shfl_xor((int)W1[mI], 32);
    }
#endif

    __builtin_amdgcn_s_setprio(1);
#pragma unroll
    for (int kt = 0; kt < 2; ++kt) {
#pragma unroll
      for (int c = 0; c < 2; ++c) {
        u32x4 fw;
#if HAS_PL32
        unsigned a0 = (kt == 0) ? W0[4 * c + 0] : W1[4 * c + 0];
        unsigned a1 = (kt == 0) ? W0[4 * c + 1] : W1[4 * c + 1];
        unsigned b0 = (kt == 0) ? W0[4 * c + 2] : W1[4 * c + 2];
        unsigned b1 = (kt == 0) ? W0[4 * c + 3] : W1[4 * c + 3];
        u32x2 pa = __builtin_amdgcn_permlane32_swap(a0, b0, false, false);
        u32x2 pb = __builtin_amdgcn_permlane32_swap(a1, b1, false, false);
        fw[0] = pa[0]; fw[1] = pb[0]; fw[2] = pa[1]; fw[3] = pb[1];
#else
        if (kt == 0) {
          fw[0] = hi ? X0[4 * c + 2] : W0[4 * c + 0];
          fw[1] = hi ? X0[4 * c + 3] : W0[4 * c + 1];
          fw[2] = hi ? W0[4 * c + 2] : X0[4 * c + 0];
          fw[3] = hi ? W0[4 * c + 3] : X0[4 * c + 1];
        } else {
          fw[0] = hi ? X1[4 * c + 2] : W1[4 * c + 0];
          fw[1] = hi ? X1[4 * c + 3] : W1[4 * c + 1];
          fw[2] = hi ? W1[4 * c + 2] : X1[4 * c + 0];
          fw[3] = hi ? W1[4 * c + 3] : X1[4 * c + 1];
        }
#endif
        bf16x8 pf = __builtin_bit_cast(bf16x8, fw);
        int ksg = (kt * 4 + c * 2 + hi) ^ l7;
        bf16x8 vfA = *(const bf16x8*)((const char*)lvt + lq * 128 + (ksg << 4));
        bf16x8 vfB = *(const bf16x8*)((const char*)lvt + (32 + lq) * 128 + (ksg << 4));
        o0 = __builtin_amdgcn_mfma_f32_32x32x16_bf16(pf, vfA, o0, 0, 0, 0);
        o1 = __builtin_amdgcn_mfma_f32_32x32x16_bf16(pf, vfB, o1, 0, 0, 0);
      }
    }
    __builtin_amdgcn_s_setprio(0);

    asm volatile("s_waitcnt lgkmcnt(0)" ::: "memory");
    BARR;
    __builtin_amdgcn_sched_barrier(0);

    if (more) {
#pragma unroll
      for (int i = 0; i < 2; ++i) {
        int idx = t + 256 * i;
        int key = idx & 63, seg = idx >> 6;
#pragma unroll
        for (int j = 0; j < 8; ++j) {
          int d = seg * 8 + j;
          lvt[d * 64 + (((key >> 3) ^ (d & 7)) << 3) + (key & 7)] = vpre[i][j];
        }
      }
    }
    asm volatile("s_waitcnt vmcnt(0) lgkmcnt(0)" ::: "memory");
    BARR;
    __builtin_amdgcn_sched_barrier(0);
  }

  const size_t cbase = (size_t)chunk * TOKENS;
#pragma unroll
  for (int r = 0; r < 16; ++r) {
    int qi = (r & 3) + 8 * (r >> 2) + 4 * hi;
    size_t rowoff = (cbase + tok0 + qb * 128 + wv * 32 + qi) * (size_t)1024 + h * DHEAD;
    Op[rowoff + lq]      = f2bf(o0[r]);
    Op[rowoff + 32 + lq] = f2bf(o1[r]);
  }
  if (l < 32) {
    size_t tokr = tok0 + qb * 128 + wv * 32 + lq;
    ml[(cbase + tokr) * 16 + h] = make_float2(mrun, lsum);
  }
}

// ---------------- combine the 2 KV-chunk partials -> bf16 attno ----------------
__global__ __launch_bounds__(256) void attn_combine2(const unsigned short* __restrict__ Op,
                                                     const float2* __restrict__ ml,
                                                     unsigned short* __restrict__ out) {
  const int t = threadIdx.x, w = t >> 6, l = t & 63;
  const size_t tok = blockIdx.x * 4 + w;
#pragma unroll
  for (int h = 0; h < 16; ++h) {
    float2 a = ml[tok * 16 + h];
    float2 c = ml[((size_t)TOKENS + tok) * 16 + h];
    float M = fmaxf(a.x, c.x);
    float w0 = EXP2(a.x - M), w1 = EXP2(c.x - M);
    float inv = 1.0f / (a.y * w0 + c.y * w1);
    int col = h * 64 + l;
    float o = (bf2f(Op[tok * 1024 + col]) * w0 +
               bf2f(Op[((size_t)TOKENS + tok) * 1024 + col]) * w1) * inv;
    out[tok * 1024 + col] = f2bf(o);
  }
}

extern "C" void kernel_launch(void* const* d_in, const int* in_sizes, int n_in,
                              void* d_out, int out_size, void* d_ws, size_t ws_size,
                              hipStream_t stream) {
  const float* x    = (const float*)d_in[0];
  const float* ln1g = (const float*)d_in[1];
  const float* ln1b = (const float*)d_in[2];
  const float* wqkv = (const float*)d_in[3];
  const float* wout = (const float*)d_in[4];
  const float* bout = (const float*)d_in[5];
  const float* ln2g = (const float*)d_in[6];
  const float* ln2b = (const float*)d_in[7];
  const float* w1   = (const float*)d_in[8];
  const float* b1   = (const float*)d_in[9];
  const float* w2   = (const float*)d_in[10];
  const float* b2   = (const float*)d_in[11];

  char* ws = (char*)d_ws;
  unsigned short* wqkvT = (unsigned short*)ws; ws += (size_t)3072 * 1024 * 2;
  unsigned short* woutT = (unsigned short*)ws; ws += (size_t)1024 * 1024 * 2;
  unsigned short* w1T   = (unsigned short*)ws; ws += (size_t)4096 * 1024 * 2;
  unsigned short* w2T   = (unsigned short*)ws; ws += (size_t)1024 * 4096 * 2;
  unsigned short* h1    = (unsigned short*)ws; ws += (size_t)TOKENS * 1024 * 2;
  unsigned short* qkvb  = (unsigned short*)ws; ws += (size_t)TOKENS * 3072 * 2;
  unsigned short* attno = (unsigned short*)ws; ws += (size_t)TOKENS * 1024 * 2;
  unsigned short* xa    = (unsigned short*)ws; ws += (size_t)TOKENS * 1024 * 4;  // bf16 (slot fp32-sized)
  unsigned short* h2    = (unsigned short*)ws; ws += (size_t)TOKENS * 1024 * 2;
  unsigned short* hid   = (unsigned short*)ws; ws += (size_t)TOKENS * 4096 * 2;
  float2*         mlbuf = (float2*)ws;         ws += (size_t)2 * TOKENS * 16 * 8;
  unsigned short* Opart = hid;  // alias: 2x bf16 partials = 16MB in hid, dead until MLP1
  unsigned short* mlp2p = h1;   // alias: 2x bf16 partials = 16MB in h1+qkvb; dead after attn4

  // 0.125 (attn scale) * log2(e) folded into W_q -> softmax in 2^x domain
  transpose_all<<<12288, 256, 0, stream>>>(wqkv, wout, w1, w2, wqkvT, woutT, w1T, w2T);

  ln_rows<<<TOKENS, 256, 0, stream>>>(x, ln1g, ln1b, h1);
  gemm_bt<0, 128, 2, 1><<<768, 256, 0, stream>>>(h1, wqkvT, qkvb, nullptr, nullptr, TOKENS, 3072, 1024);
  attn4<<<dim3(2 * SEQ / 128, HEADS, BATCH), 256, 0, stream>>>(qkvb, Opart, mlbuf);
  attn_combine2<<<TOKENS / 4, 256, 0, stream>>>(Opart, mlbuf, attno);
  gemm_bt<3, 64, 3, 1><<<512, 256, 0, stream>>>(attno, woutT, xa, bout, x, TOKENS, 1024, 1024);
  ln_rows_bf<<<TOKENS, 256, 0, stream>>>(xa, ln2g, ln2b, h2);
  gemm_bt<2, 128, 2, 1><<<1024, 256, 0, stream>>>(h2, w1T, hid, b1, nullptr, TOKENS, 4096, 1024);
  // MLP2 split-K x2, BN=128, bf16 partials
  gemm_bt<5, 128, 2, 2><<<512, 256, 0, stream>>>(hid, w2T, mlp2p, nullptr, nullptr, TOKENS, 1024, 4096);
  mlp2_combine<<<TOKENS, 256, 0, stream>>>(mlp2p, b2, xa, (float*)d_out);
}

// Round 20
// 232.163 us; speedup vs baseline: 1.1382x; 1.0054x over previous
//
#include <hip/hip_runtime.h>
#include <hip/hip_bf16.h>
#include <math.h>

#define SEQ 2048
#define BATCH 2
#define TOKENS 4096
#define HEADS 16
#define DHEAD 64
#define TOKSTRIDE 3072

typedef __attribute__((ext_vector_type(4))) float f32x4;
typedef __attribute__((ext_vector_type(16))) float f32x16;
typedef __attribute__((ext_vector_type(8))) __bf16 bf16x8;
typedef __attribute__((ext_vector_type(8))) unsigned short ushort8;
typedef __attribute__((ext_vector_type(4))) unsigned short ushort4_t;
typedef __attribute__((ext_vector_type(4))) unsigned u32x4;
typedef __attribute__((ext_vector_type(2))) unsigned u32x2;

#if __has_builtin(__builtin_amdgcn_exp2f)
#define EXP2(x) __builtin_amdgcn_exp2f(x)
#else
#define EXP2(x) exp2f(x)
#endif

#if __has_builtin(__builtin_amdgcn_permlane32_swap)
#define HAS_PL32 1
#else
#define HAS_PL32 0
#endif

__device__ __forceinline__ unsigned short f2bf(float f) {
  unsigned u = __builtin_bit_cast(unsigned, f);
  u += 0x7fffu + ((u >> 16) & 1u);
  return (unsigned short)(u >> 16);
}

__device__ __forceinline__ float bf2f(unsigned short s) {
  unsigned u = ((unsigned)s) << 16;
  return __builtin_bit_cast(float, u);
}

__device__ __forceinline__ unsigned cvt_pk_bf16(float lo, float hi) {
  unsigned r;
  asm("v_cvt_pk_bf16_f32 %0, %1, %2" : "=v"(r) : "v"(lo), "v"(hi));
  return r;
}

__device__ __forceinline__ void cp16(const void* g, void* l) {
  __builtin_amdgcn_global_load_lds((const __attribute__((address_space(1))) void*)g,
                                   (__attribute__((address_space(3))) void*)l, 16, 0, 0);
}

#define FENCE asm volatile("" ::: "memory")
#define BARR  do { FENCE; __builtin_amdgcn_s_barrier(); FENCE; } while (0)

// ---- prep: 4 weight transposes (bid<12288) + LN1 rows (bid>=12288), one launch ----
// Transpose: fp32 [K][N] -> bf16 [N][K]; W_q rows get *0.125*log2e (exp2-domain SM).
// LN: row = bid-12288, fp32 x -> bf16 h1.
__global__ __launch_bounds__(256) void prep_all(
    const float* __restrict__ wqkv, const float* __restrict__ wout,
    const float* __restrict__ w1, const float* __restrict__ w2,
    unsigned short* __restrict__ wqkvT, unsigned short* __restrict__ woutT,
    unsigned short* __restrict__ w1T, unsigned short* __restrict__ w2T,
    const float* __restrict__ x, const float* __restrict__ g,
    const float* __restrict__ b, unsigned short* __restrict__ h1) {
  __shared__ float tile[32][33];
  const int bid = blockIdx.x;
  if (bid >= 12288) {  // ---- LayerNorm branch ----
    const int row = bid - 12288;
    const int t = threadIdx.x;
    const f32x4* x4 = (const f32x4*)(x + (size_t)row * 1024);
    f32x4 v = x4[t];
    float sum = v[0] + v[1] + v[2] + v[3];
    float ss  = v[0]*v[0] + v[1]*v[1] + v[2]*v[2] + v[3]*v[3];
#pragma unroll
    for (int off = 1; off < 64; off <<= 1) {
      sum += __shfl_xor(sum, off);
      ss  += __shfl_xor(ss, off);
    }
    float* red = &tile[0][0];
    const int w = t >> 6, l = t & 63;
    if (l == 0) { red[w] = sum; red[w + 4] = ss; }
    __syncthreads();
    sum = red[0] + red[1] + red[2] + red[3];
    ss  = red[4] + red[5] + red[6] + red[7];
    const float mean = sum * (1.0f / 1024.0f);
    const float var  = ss * (1.0f / 1024.0f) - mean * mean;
    const float rs = rsqrtf(var + 1e-5f);
    ushort4_t o;
#pragma unroll
    for (int j = 0; j < 4; ++j) {
      float gv = g[t * 4 + j], bv = b[t * 4 + j];
      o[j] = f2bf((v[j] - mean) * rs * gv + bv);
    }
    *(ushort4_t*)(h1 + (size_t)row * 1024 + t * 4) = o;
    return;
  }
  // ---- transpose branch ----
  const float* w; unsigned short* wt; int K, N, lb; float scale; int nscaled;
  if (bid < 3072)      { w = wqkv; wt = wqkvT; K = 1024; N = 3072; lb = bid;        scale = 0.18033688f; nscaled = 1024; }
  else if (bid < 4096) { w = wout; wt = woutT; K = 1024; N = 1024; lb = bid - 3072; scale = 1.0f; nscaled = 0; }
  else if (bid < 8192) { w = w1;   wt = w1T;   K = 1024; N = 4096; lb = bid - 4096; scale = 1.0f; nscaled = 0; }
  else                 { w = w2;   wt = w2T;   K = 4096; N = 1024; lb = bid - 8192; scale = 1.0f; nscaled = 0; }
  const int nx = N / 32;
  const int n0 = (lb % nx) * 32, k0 = (lb / nx) * 32;
  const int tx = threadIdx.x & 31;
  const int ty = threadIdx.x >> 5;  // 0..7
#pragma unroll
  for (int i = 0; i < 4; ++i)
    tile[ty + 8 * i][tx] = w[(size_t)(k0 + ty + 8 * i) * N + n0 + tx];
  __syncthreads();
#pragma unroll
  for (int i = 0; i < 4; ++i) {
    int n = n0 + ty + 8 * i;
    float s = (n < nscaled) ? scale : 1.0f;
    wt[(size_t)n * K + k0 + tx] = f2bf(tile[tx][ty + 8 * i] * s);
  }
}

// ---------------- LayerNorm, bf16 in -> bf16 out ----------------
__global__ __launch_bounds__(256) void ln_rows_bf(const unsigned short* __restrict__ x,
                                                  const float* __restrict__ g,
                                                  const float* __restrict__ b,
                                                  unsigned short* __restrict__ out) {
  const int row = blockIdx.x;
  const int t = threadIdx.x;
  ushort4_t v4 = *(const ushort4_t*)(x + (size_t)row * 1024 + t * 4);
  float v[4] = {bf2f(v4[0]), bf2f(v4[1]), bf2f(v4[2]), bf2f(v4[3])};
  float sum = v[0] + v[1] + v[2] + v[3];
  float ss  = v[0]*v[0] + v[1]*v[1] + v[2]*v[2] + v[3]*v[3];
#pragma unroll
  for (int off = 1; off < 64; off <<= 1) {
    sum += __shfl_xor(sum, off);
    ss  += __shfl_xor(ss, off);
  }
  __shared__ float red[8];
  const int w = t >> 6, l = t & 63;
  if (l == 0) { red[w] = sum; red[w + 4] = ss; }
  __syncthreads();
  sum = red[0] + red[1] + red[2] + red[3];
  ss  = red[4] + red[5] + red[6] + red[7];
  const float mean = sum * (1.0f / 1024.0f);
  const float var  = ss * (1.0f / 1024.0f) - mean * mean;
  const float rs = rsqrtf(var + 1e-5f);
  ushort4_t o;
#pragma unroll
  for (int j = 0; j < 4; ++j) {
    float gv = g[t * 4 + j], bv = b[t * 4 + j];
    o[j] = f2bf((v[j] - mean) * rs * gv + bv);
  }
  *(ushort4_t*)(out + (size_t)row * 1024 + t * 4) = o;
}

// ---------------- GEMM (R6-proven 2-phase): C[M,N] = A[M,K] * Bt[N,K]^T ----------------
// EPI: 0 = bf16 ; 2 = bf16 gelu(acc+bias) ; 3 = bf16 acc+bias+res_fp32 ;
//      4 = fp32 acc+bias+res_bf16 ; 5 = bf16 raw-acc partial (split-K slice ksl)
template <int EPI, int BN, int MINW, int NSPLIT>
__global__ __launch_bounds__(256, MINW) void gemm_bt(
    const unsigned short* __restrict__ A, const unsigned short* __restrict__ Bt,
    void* __restrict__ Cp, const float* __restrict__ bias, const void* __restrict__ resv,
    int M, int N, int K) {
  constexpr int BM = 128, BK = 64;
  constexpr int MR = BM / 32, NR = BN / 32;
  constexpr int AIT = BM * BK / 2048;
  constexpr int BIT = BN * BK / 2048;
  __shared__ unsigned short la[BM * BK];
  __shared__ unsigned short lb[BN * BK];
  const int t = threadIdx.x;
  const int w = t >> 6, l = t & 63;
  const int nwg = gridDim.x;
  const int bid = blockIdx.x;
  const int bid2 = (bid & 7) * (nwg >> 3) + (bid >> 3);  // XCD swizzle (nwg%8==0)
  const int nmn = nwg / NSPLIT;
  const int ksl = bid2 / nmn;
  const int rmn = bid2 - ksl * nmn;
  const int nx = N / BN;
  const int m0 = (rmn / nx) * BM, n0 = (rmn % nx) * BN;
  const int klen = K / NSPLIT;
  const int kbeg = ksl * klen;
  const int wr = w >> 1, wc = w & 1;
  const int lrow = l & 15, lk4 = l >> 4;
  f32x4 acc[MR][NR] = {};

  for (int k0 = kbeg; k0 < kbeg + klen; k0 += BK) {
#pragma unroll
    for (int i = 0; i < AIT; ++i) {
      int idx = t + 256 * i;
      int row = idx >> 3, seg = idx & 7;
      int ss = seg ^ (row & 7);
      cp16(A + (size_t)(m0 + row) * K + k0 + ss * 8, (char*)la + w * 1024 + i * 4096);
    }
#pragma unroll
    for (int i = 0; i < BIT; ++i) {
      int idx = t + 256 * i;
      int row = idx >> 3, seg = idx & 7;
      int ss = seg ^ (row & 7);
      cp16(Bt + (size_t)(n0 + row) * K + k0 + ss * 8, (char*)lb + w * 1024 + i * 4096);
    }
    __syncthreads();
#pragma unroll
    for (int ks = 0; ks < 2; ++ks) {
      bf16x8 af[MR], bfr[NR];
#pragma unroll
      for (int mi = 0; mi < MR; ++mi) {
        int row = wr * (BM / 2) + mi * 16 + lrow;
        int ss = (ks * 4 + lk4) ^ (row & 7);
        af[mi] = *(const bf16x8*)((const char*)la + row * 128 + ss * 16);
      }
#pragma unroll
      for (int ni = 0; ni < NR; ++ni) {
        int row = wc * (BN / 2) + ni * 16 + lrow;
        int ss = (ks * 4 + lk4) ^ (row & 7);
        bfr[ni] = *(const bf16x8*)((const char*)lb + row * 128 + ss * 16);
      }
#pragma unroll
      for (int mi = 0; mi < MR; ++mi)
#pragma unroll
        for (int ni = 0; ni < NR; ++ni)
          acc[mi][ni] = __builtin_amdgcn_mfma_f32_16x16x32_bf16(af[mi], bfr[ni], acc[mi][ni], 0, 0, 0);
    }
    __syncthreads();
  }

#pragma unroll
  for (int mi = 0; mi < MR; ++mi) {
    int rowb = m0 + wr * (BM / 2) + mi * 16 + lk4 * 4;
#pragma unroll
    for (int ni = 0; ni < NR; ++ni) {
      int col = n0 + wc * (BN / 2) + ni * 16 + lrow;
      f32x4 a = acc[mi][ni];
#pragma unroll
      for (int r = 0; r < 4; ++r) {
        size_t off = (size_t)(rowb + r) * N + col;
        if (EPI == 0) {
          ((unsigned short*)Cp)[off] = f2bf(a[r]);
        } else if (EPI == 2) {
          float v = a[r] + bias[col];
          ((unsigned short*)Cp)[off] = f2bf(0.5f * v * (1.0f + erff(v * 0.70710678f)));
        } else if (EPI == 3) {
          ((unsigned short*)Cp)[off] = f2bf(a[r] + bias[col] + ((const float*)resv)[off]);
        } else if (EPI == 4) {
          ((float*)Cp)[off] = a[r] + bias[col] + bf2f(((const unsigned short*)resv)[off]);
        } else {  // EPI == 5: bf16 partial for split-K
          ((unsigned short*)Cp)[(size_t)ksl * M * N + off] = f2bf(a[r]);
        }
      }
    }
  }
}

// ------- split-K(2) combine for MLP2: out = p0 + p1 + b2 + residual(bf16) -------
__global__ __launch_bounds__(256) void mlp2_combine(const unsigned short* __restrict__ p,
                                                    const float* __restrict__ b2,
                                                    const unsigned short* __restrict__ xa,
                                                    float* __restrict__ out) {
  const int row = blockIdx.x, t = threadIdx.x;
  const size_t off = (size_t)row * 1024 + t * 4;
  ushort4_t a = *(const ushort4_t*)(p + off);
  ushort4_t b = *(const ushort4_t*)(p + (size_t)TOKENS * 1024 + off);
  f32x4 bb = *(const f32x4*)(b2 + t * 4);
  ushort4_t xv = *(const ushort4_t*)(xa + off);
  f32x4 o;
#pragma unroll
  for (int j = 0; j < 4; ++j) o[j] = bf2f(a[j]) + bf2f(b[j]) + bb[j] + bf2f(xv[j]);
  *(f32x4*)(out + off) = o;
}

// ---------------- fused flash attention, KV-split x2, single-buffered LDS ----------
// Single-buffer body is the measured best (R14 vs R15: -10us vs dbuf). Split x2
// halves the partial-combine traffic vs x4 (split factor itself ~neutral, R19).
__global__ __launch_bounds__(256, 2) void attn4(const unsigned short* __restrict__ qkv,
                                                unsigned short* __restrict__ Op,
                                                float2* __restrict__ ml) {
  __shared__ unsigned short lk_[64 * 64];  // K [key][d], seg^(key&7) swizzled
  __shared__ unsigned short lvt[64 * 64];  // V^T [d][key], kseg^(d&7) swizzled
  const int t = threadIdx.x, wv = t >> 6, l = t & 63;
  const int chunk = blockIdx.x & 1, qb = blockIdx.x >> 1;
  const int h = blockIdx.y, b = blockIdx.z;
  const size_t tok0 = (size_t)b * SEQ;
  const int lq = l & 31, hi = l >> 5, l7 = l & 7;
  const int qrow = qb * 128 + wv * 32 + lq;
  const int kstart = chunk * 16;  // 16 tiles of 64 keys per chunk

  bf16x8 qf[4];
#pragma unroll
  for (int dc = 0; dc < 4; ++dc)
    qf[dc] = *(const bf16x8*)(qkv + (tok0 + qrow) * TOKSTRIDE + h * DHEAD + dc * 16 + hi * 8);

  float mrun = -1e30f, lsum = 0.0f;
  f32x16 o0 = {}, o1 = {};

  {
#pragma unroll
    for (int i = 0; i < 2; ++i) {
      int idx = t + 256 * i;
      int key = idx >> 3, seg = idx & 7;
      cp16(qkv + (tok0 + kstart * 64 + key) * TOKSTRIDE + 1024 + h * DHEAD + ((seg ^ (key & 7)) << 3),
           (char*)lk_ + wv * 1024 + i * 4096);
    }
#pragma unroll
    for (int i = 0; i < 2; ++i) {
      int idx = t + 256 * i;
      int key = idx & 63, seg = idx >> 6;
      ushort8 v8 = *(const ushort8*)(qkv + (tok0 + kstart * 64 + key) * TOKSTRIDE + 2048 + h * DHEAD + seg * 8);
#pragma unroll
      for (int j = 0; j < 8; ++j) {
        int d = seg * 8 + j;
        lvt[d * 64 + (((key >> 3) ^ (d & 7)) << 3) + (key & 7)] = v8[j];
      }
    }
  }
  __syncthreads();

  for (int kb = 0; kb < 16; ++kb) {
    const bool more = (kb + 1 < 16);
    const int kpre = kstart + kb + 1;

    f32x16 s0 = {}, s1 = {};
    __builtin_amdgcn_s_setprio(1);
#pragma unroll
    for (int dc = 0; dc < 4; ++dc) {
      int sgA = (dc * 2 + hi) ^ l7;
      bf16x8 kf0 = *(const bf16x8*)((const char*)lk_ + lq * 128 + (sgA << 4));
      bf16x8 kf1 = *(const bf16x8*)((const char*)lk_ + (32 + lq) * 128 + (sgA << 4));
      s0 = __builtin_amdgcn_mfma_f32_32x32x16_bf16(kf0, qf[dc], s0, 0, 0, 0);
      s1 = __builtin_amdgcn_mfma_f32_32x32x16_bf16(kf1, qf[dc], s1, 0, 0, 0);
    }
    __builtin_amdgcn_s_setprio(0);

    asm volatile("s_waitcnt lgkmcnt(0)" ::: "memory");
    BARR;
    __builtin_amdgcn_sched_barrier(0);

    ushort8 vpre[2];
    if (more) {
#pragma unroll
      for (int i = 0; i < 2; ++i) {
        int idx = t + 256 * i;
        int key = idx >> 3, seg = idx & 7;
        cp16(qkv + (tok0 + kpre * 64 + key) * TOKSTRIDE + 1024 + h * DHEAD + ((seg ^ (key & 7)) << 3),
             (char*)lk_ + wv * 1024 + i * 4096);
      }
#pragma unroll
      for (int i = 0; i < 2; ++i) {
        int idx = t + 256 * i;
        int key = idx & 63, seg = idx >> 6;
        vpre[i] = *(const ushort8*)(qkv + (tok0 + kpre * 64 + key) * TOKSTRIDE + 2048 + h * DHEAD + seg * 8);
      }
    }

    float mx[8];
#pragma unroll
    for (int r = 0; r < 8; ++r)
      mx[r] = fmaxf(fmaxf(s0[r], s0[r + 8]), fmaxf(s1[r], s1[r + 8]));
#pragma unroll
    for (int r = 0; r < 4; ++r) mx[r] = fmaxf(mx[r], mx[r + 4]);
    float m01 = fmaxf(fmaxf(mx[0], mx[1]), fmaxf(mx[2], mx[3]));
    float pm = fmaxf(m01, __shfl_xor(m01, 32));

    if (__any(pm > mrun + 8.0f)) {
      float mn = fmaxf(mrun, pm);
      float alpha = EXP2(mrun - mn);
      mrun = mn;
      lsum *= alpha;
#pragma unroll
      for (int r = 0; r < 16; ++r) {
        int qi = (r & 3) + 8 * (r >> 2) + 4 * hi;
        float ar = __shfl(alpha, qi);
        o0[r] *= ar; o1[r] *= ar;
      }
    }

    float p0[16], p1[16], ts[16];
#pragma unroll
    for (int r = 0; r < 16; ++r) { p0[r] = EXP2(s0[r] - mrun); }
#pragma unroll
    for (int r = 0; r < 16; ++r) { p1[r] = EXP2(s1[r] - mrun); }
#pragma unroll
    for (int r = 0; r < 16; ++r) ts[r] = p0[r] + p1[r];
#pragma unroll
    for (int st = 8; st > 0; st >>= 1)
#pragma unroll
      for (int r = 0; r < 8; ++r)
        if (r < st) ts[r] += ts[r + st];
    float psum = ts[0] + __shfl_xor(ts[0], 32);
    lsum += psum;

    unsigned W0[8], W1[8];
#pragma unroll
    for (int mI = 0; mI < 8; ++mI) {
      W0[mI] = cvt_pk_bf16(p0[2 * mI], p0[2 * mI + 1]);
      W1[mI] = cvt_pk_bf16(p1[2 * mI], p1[2 * mI + 1]);
    }
#if !HAS_PL32
    unsigned X0[8], X1[8];
#pragma unroll
    for (int mI = 0; mI < 8; ++mI) {
      X0[mI] = __shfl_xor((int)W0[mI], 32);
      X1[mI] = __shfl_xor((int)W1[mI], 32);
    }
#endif

    __builtin_amdgcn_s_setprio(1);
#pragma unroll
    for (int kt = 0; kt < 2; ++kt) {
#pragma unroll
      for (int c = 0; c < 2; ++c) {
        u32x4 fw;
#if HAS_PL32
        unsigned a0 = (kt == 0) ? W0[4 * c + 0] : W1[4 * c + 0];
        unsigned a1 = (kt == 0) ? W0[4 * c + 1] : W1[4 * c + 1];
        unsigned b0 = (kt == 0) ? W0[4 * c + 2] : W1[4 * c + 2];
        unsigned b1 = (kt == 0) ? W0[4 * c + 3] : W1[4 * c + 3];
        u32x2 pa = __builtin_amdgcn_permlane32_swap(a0, b0, false, false);
        u32x2 pb = __builtin_amdgcn_permlane32_swap(a1, b1, false, false);
        fw[0] = pa[0]; fw[1] = pb[0]; fw[2] = pa[1]; fw[3] = pb[1];
#else
        if (kt == 0) {
          fw[0] = hi ? X0[4 * c + 2] : W0[4 * c + 0];
          fw[1] = hi ? X0[4 * c + 3] : W0[4 * c + 1];
          fw[2] = hi ? W0[4 * c + 2] : X0[4 * c + 0];
          fw[3] = hi ? W0[4 * c + 3] : X0[4 * c + 1];
        } else {
          fw[0] = hi ? X1[4 * c + 2] : W1[4 * c + 0];
          fw[1] = hi ? X1[4 * c + 3] : W1[4 * c + 1];
          fw[2] = hi ? W1[4 * c + 2] : X1[4 * c + 0];
          fw[3] = hi ? W1[4 * c + 3] : X1[4 * c + 1];
        }
#endif
        bf16x8 pf = __builtin_bit_cast(bf16x8, fw);
        int ksg = (kt * 4 + c * 2 + hi) ^ l7;
        bf16x8 vfA = *(const bf16x8*)((const char*)lvt + lq * 128 + (ksg << 4));
        bf16x8 vfB = *(const bf16x8*)((const char*)lvt + (32 + lq) * 128 + (ksg << 4));
        o0 = __builtin_amdgcn_mfma_f32_32x32x16_bf16(pf, vfA, o0, 0, 0, 0);
        o1 = __builtin_amdgcn_mfma_f32_32x32x16_bf16(pf, vfB, o1, 0, 0, 0);
      }
    }
    __builtin_amdgcn_s_setprio(0);

    asm volatile("s_waitcnt lgkmcnt(0)" ::: "memory");
    BARR;
    __builtin_amdgcn_sched_barrier(0);

    if (more) {
#pragma unroll
      for (int i = 0; i < 2; ++i) {
        int idx = t + 256 * i;
        int key = idx & 63, seg = idx >> 6;
#pragma unroll
        for (int j = 0; j < 8; ++j) {
          int d = seg * 8 + j;
          lvt[d * 64 + (((key >> 3) ^ (d & 7)) << 3) + (key & 7)] = vpre[i][j];
        }
      }
    }
    asm volatile("s_waitcnt vmcnt(0) lgkmcnt(0)" ::: "memory");
    BARR;
    __builtin_amdgcn_sched_barrier(0);
  }

  const size_t cbase = (size_t)chunk * TOKENS;
#pragma unroll
  for (int r = 0; r < 16; ++r) {
    int qi = (r & 3) + 8 * (r >> 2) + 4 * hi;
    size_t rowoff = (cbase + tok0 + qb * 128 + wv * 32 + qi) * (size_t)1024 + h * DHEAD;
    Op[rowoff + lq]      = f2bf(o0[r]);
    Op[rowoff + 32 + lq] = f2bf(o1[r]);
  }
  if (l < 32) {
    size_t tokr = tok0 + qb * 128 + wv * 32 + lq;
    ml[(cbase + tokr) * 16 + h] = make_float2(mrun, lsum);
  }
}

// ---------------- combine the 2 KV-chunk partials -> bf16 attno ----------------
__global__ __launch_bounds__(256) void attn_combine2(const unsigned short* __restrict__ Op,
                                                     const float2* __restrict__ ml,
                                                     unsigned short* __restrict__ out) {
  const int t = threadIdx.x, w = t >> 6, l = t & 63;
  const size_t tok = blockIdx.x * 4 + w;
#pragma unroll
  for (int h = 0; h < 16; ++h) {
    float2 a = ml[tok * 16 + h];
    float2 c = ml[((size_t)TOKENS + tok) * 16 + h];
    float M = fmaxf(a.x, c.x);
    float w0 = EXP2(a.x - M), w1 = EXP2(c.x - M);
    float inv = 1.0f / (a.y * w0 + c.y * w1);
    int col = h * 64 + l;
    float o = (bf2f(Op[tok * 1024 + col]) * w0 +
               bf2f(Op[((size_t)TOKENS + tok) * 1024 + col]) * w1) * inv;
    out[tok * 1024 + col] = f2bf(o);
  }
}

extern "C" void kernel_launch(void* const* d_in, const int* in_sizes, int n_in,
                              void* d_out, int out_size, void* d_ws, size_t ws_size,
                              hipStream_t stream) {
  const float* x    = (const float*)d_in[0];
  const float* ln1g = (const float*)d_in[1];
  const float* ln1b = (const float*)d_in[2];
  const float* wqkv = (const float*)d_in[3];
  const float* wout = (const float*)d_in[4];
  const float* bout = (const float*)d_in[5];
  const float* ln2g = (const float*)d_in[6];
  const float* ln2b = (const float*)d_in[7];
  const float* w1   = (const float*)d_in[8];
  const float* b1   = (const float*)d_in[9];
  const float* w2   = (const float*)d_in[10];
  const float* b2   = (const float*)d_in[11];

  char* ws = (char*)d_ws;
  unsigned short* wqkvT = (unsigned short*)ws; ws += (size_t)3072 * 1024 * 2;
  unsigned short* woutT = (unsigned short*)ws; ws += (size_t)1024 * 1024 * 2;
  unsigned short* w1T   = (unsigned short*)ws; ws += (size_t)4096 * 1024 * 2;
  unsigned short* w2T   = (unsigned short*)ws; ws += (size_t)1024 * 4096 * 2;
  unsigned short* h1    = (unsigned short*)ws; ws += (size_t)TOKENS * 1024 * 2;
  unsigned short* qkvb  = (unsigned short*)ws; ws += (size_t)TOKENS * 3072 * 2;
  unsigned short* attno = (unsigned short*)ws; ws += (size_t)TOKENS * 1024 * 2;
  unsigned short* xa    = (unsigned short*)ws; ws += (size_t)TOKENS * 1024 * 4;  // bf16 (slot fp32-sized)
  unsigned short* h2    = (unsigned short*)ws; ws += (size_t)TOKENS * 1024 * 2;
  unsigned short* hid   = (unsigned short*)ws; ws += (size_t)TOKENS * 4096 * 2;
  float2*         mlbuf = (float2*)ws;         ws += (size_t)2 * TOKENS * 16 * 8;
  unsigned short* Opart = hid;  // alias: 2x bf16 partials = 16MB in hid, dead until MLP1
  unsigned short* mlp2p = h1;   // alias: 2x bf16 partials = 16MB in h1+qkvb; dead after attn4

  // prep: weight transposes (W_q pre-scaled by 0.125*log2e) + LN1, one launch
  prep_all<<<12288 + TOKENS, 256, 0, stream>>>(wqkv, wout, w1, w2, wqkvT, woutT, w1T, w2T,
                                               x, ln1g, ln1b, h1);
  gemm_bt<0, 128, 2, 1><<<768, 256, 0, stream>>>(h1, wqkvT, qkvb, nullptr, nullptr, TOKENS, 3072, 1024);
  attn4<<<dim3(2 * SEQ / 128, HEADS, BATCH), 256, 0, stream>>>(qkvb, Opart, mlbuf);
  attn_combine2<<<TOKENS / 4, 256, 0, stream>>>(Opart, mlbuf, attno);
  gemm_bt<3, 64, 3, 1><<<512, 256, 0, stream>>>(attno, woutT, xa, bout, x, TOKENS, 1024, 1024);
  ln_rows_bf<<<TOKENS, 256, 0, stream>>>(xa, ln2g, ln2b, h2);
  gemm_bt<2, 128, 2, 1><<<1024, 256, 0, stream>>>(h2, w1T, hid, b1, nullptr, TOKENS, 4096, 1024);
  // MLP2 split-K x2, BN=128, bf16 partials
  gemm_bt<5, 128, 2, 2><<<512, 256, 0, stream>>>(hid, w2T, mlp2p, nullptr, nullptr, TOKENS, 1024, 4096);
  mlp2_combine<<<TOKENS, 256, 0, stream>>>(mlp2p, b2, xa, (float*)d_out);
}

// Round 21
// 231.855 us; speedup vs baseline: 1.1397x; 1.0013x over previous
//
#include <hip/hip_runtime.h>
#include <hip/hip_bf16.h>
#include <math.h>

#define SEQ 2048
#define BATCH 2
#define TOKENS 4096
#define HEADS 16
#define DHEAD 64
#define TOKSTRIDE 3072

typedef __attribute__((ext_vector_type(4))) float f32x4;
typedef __attribute__((ext_vector_type(16))) float f32x16;
typedef __attribute__((ext_vector_type(8))) __bf16 bf16x8;
typedef __attribute__((ext_vector_type(8))) unsigned short ushort8;
typedef __attribute__((ext_vector_type(4))) unsigned short ushort4_t;
typedef __attribute__((ext_vector_type(4))) unsigned u32x4;
typedef __attribute__((ext_vector_type(2))) unsigned u32x2;

#if __has_builtin(__builtin_amdgcn_exp2f)
#define EXP2(x) __builtin_amdgcn_exp2f(x)
#else
#define EXP2(x) exp2f(x)
#endif

#if __has_builtin(__builtin_amdgcn_permlane32_swap)
#define HAS_PL32 1
#else
#define HAS_PL32 0
#endif

__device__ __forceinline__ unsigned short f2bf(float f) {
  unsigned u = __builtin_bit_cast(unsigned, f);
  u += 0x7fffu + ((u >> 16) & 1u);
  return (unsigned short)(u >> 16);
}

__device__ __forceinline__ float bf2f(unsigned short s) {
  unsigned u = ((unsigned)s) << 16;
  return __builtin_bit_cast(float, u);
}

__device__ __forceinline__ unsigned cvt_pk_bf16(float lo, float hi) {
  unsigned r;
  asm("v_cvt_pk_bf16_f32 %0, %1, %2" : "=v"(r) : "v"(lo), "v"(hi));
  return r;
}

__device__ __forceinline__ void cp16(const void* g, void* l) {
  __builtin_amdgcn_global_load_lds((const __attribute__((address_space(1))) void*)g,
                                   (__attribute__((address_space(3))) void*)l, 16, 0, 0);
}

#define FENCE asm volatile("" ::: "memory")
#define BARR  do { FENCE; __builtin_amdgcn_s_barrier(); FENCE; } while (0)

// ---- prep: 4 weight transposes (bid<12288) + LN1 rows (bid>=12288), one launch ----
__global__ __launch_bounds__(256) void prep_all(
    const float* __restrict__ wqkv, const float* __restrict__ wout,
    const float* __restrict__ w1, const float* __restrict__ w2,
    unsigned short* __restrict__ wqkvT, unsigned short* __restrict__ woutT,
    unsigned short* __restrict__ w1T, unsigned short* __restrict__ w2T,
    const float* __restrict__ x, const float* __restrict__ g,
    const float* __restrict__ b, unsigned short* __restrict__ h1) {
  __shared__ float tile[32][33];
  const int bid = blockIdx.x;
  if (bid >= 12288) {  // ---- LayerNorm branch ----
    const int row = bid - 12288;
    const int t = threadIdx.x;
    const f32x4* x4 = (const f32x4*)(x + (size_t)row * 1024);
    f32x4 v = x4[t];
    float sum = v[0] + v[1] + v[2] + v[3];
    float ss  = v[0]*v[0] + v[1]*v[1] + v[2]*v[2] + v[3]*v[3];
#pragma unroll
    for (int off = 1; off < 64; off <<= 1) {
      sum += __shfl_xor(sum, off);
      ss  += __shfl_xor(ss, off);
    }
    float* red = &tile[0][0];
    const int w = t >> 6, l = t & 63;
    if (l == 0) { red[w] = sum; red[w + 4] = ss; }
    __syncthreads();
    sum = red[0] + red[1] + red[2] + red[3];
    ss  = red[4] + red[5] + red[6] + red[7];
    const float mean = sum * (1.0f / 1024.0f);
    const float var  = ss * (1.0f / 1024.0f) - mean * mean;
    const float rs = rsqrtf(var + 1e-5f);
    ushort4_t o;
#pragma unroll
    for (int j = 0; j < 4; ++j) {
      float gv = g[t * 4 + j], bv = b[t * 4 + j];
      o[j] = f2bf((v[j] - mean) * rs * gv + bv);
    }
    *(ushort4_t*)(h1 + (size_t)row * 1024 + t * 4) = o;
    return;
  }
  // ---- transpose branch ----
  const float* w; unsigned short* wt; int K, N, lb; float scale; int nscaled;
  if (bid < 3072)      { w = wqkv; wt = wqkvT; K = 1024; N = 3072; lb = bid;        scale = 0.18033688f; nscaled = 1024; }
  else if (bid < 4096) { w = wout; wt = woutT; K = 1024; N = 1024; lb = bid - 3072; scale = 1.0f; nscaled = 0; }
  else if (bid < 8192) { w = w1;   wt = w1T;   K = 1024; N = 4096; lb = bid - 4096; scale = 1.0f; nscaled = 0; }
  else                 { w = w2;   wt = w2T;   K = 4096; N = 1024; lb = bid - 8192; scale = 1.0f; nscaled = 0; }
  const int nx = N / 32;
  const int n0 = (lb % nx) * 32, k0 = (lb / nx) * 32;
  const int tx = threadIdx.x & 31;
  const int ty = threadIdx.x >> 5;  // 0..7
#pragma unroll
  for (int i = 0; i < 4; ++i)
    tile[ty + 8 * i][tx] = w[(size_t)(k0 + ty + 8 * i) * N + n0 + tx];
  __syncthreads();
#pragma unroll
  for (int i = 0; i < 4; ++i) {
    int n = n0 + ty + 8 * i;
    float s = (n < nscaled) ? scale : 1.0f;
    wt[(size_t)n * K + k0 + tx] = f2bf(tile[tx][ty + 8 * i] * s);
  }
}

// ---------------- LayerNorm, bf16 in -> bf16 out ----------------
__global__ __launch_bounds__(256) void ln_rows_bf(const unsigned short* __restrict__ x,
                                                  const float* __restrict__ g,
                                                  const float* __restrict__ b,
                                                  unsigned short* __restrict__ out) {
  const int row = blockIdx.x;
  const int t = threadIdx.x;
  ushort4_t v4 = *(const ushort4_t*)(x + (size_t)row * 1024 + t * 4);
  float v[4] = {bf2f(v4[0]), bf2f(v4[1]), bf2f(v4[2]), bf2f(v4[3])};
  float sum = v[0] + v[1] + v[2] + v[3];
  float ss  = v[0]*v[0] + v[1]*v[1] + v[2]*v[2] + v[3]*v[3];
#pragma unroll
  for (int off = 1; off < 64; off <<= 1) {
    sum += __shfl_xor(sum, off);
    ss  += __shfl_xor(ss, off);
  }
  __shared__ float red[8];
  const int w = t >> 6, l = t & 63;
  if (l == 0) { red[w] = sum; red[w + 4] = ss; }
  __syncthreads();
  sum = red[0] + red[1] + red[2] + red[3];
  ss  = red[4] + red[5] + red[6] + red[7];
  const float mean = sum * (1.0f / 1024.0f);
  const float var  = ss * (1.0f / 1024.0f) - mean * mean;
  const float rs = rsqrtf(var + 1e-5f);
  ushort4_t o;
#pragma unroll
  for (int j = 0; j < 4; ++j) {
    float gv = g[t * 4 + j], bv = b[t * 4 + j];
    o[j] = f2bf((v[j] - mean) * rs * gv + bv);
  }
  *(ushort4_t*)(out + (size_t)row * 1024 + t * 4) = o;
}

// ---------------- GEMM (R6-proven 2-phase): C[M,N] = A[M,K] * Bt[N,K]^T ----------------
// EPI: 0 = bf16 ; 2 = bf16 gelu(acc+bias) ; 3 = bf16 acc+bias+res_fp32 ;
//      4 = fp32 acc+bias+res_bf16 ; 5 = bf16 raw-acc partial (split-K slice ksl)
template <int EPI, int BN, int MINW, int NSPLIT>
__global__ __launch_bounds__(256, MINW) void gemm_bt(
    const unsigned short* __restrict__ A, const unsigned short* __restrict__ Bt,
    void* __restrict__ Cp, const float* __restrict__ bias, const void* __restrict__ resv,
    int M, int N, int K) {
  constexpr int BM = 128, BK = 64;
  constexpr int MR = BM / 32, NR = BN / 32;
  constexpr int AIT = BM * BK / 2048;
  constexpr int BIT = BN * BK / 2048;
  __shared__ unsigned short la[BM * BK];
  __shared__ unsigned short lb[BN * BK];
  const int t = threadIdx.x;
  const int w = t >> 6, l = t & 63;
  const int nwg = gridDim.x;
  const int bid = blockIdx.x;
  const int bid2 = (bid & 7) * (nwg >> 3) + (bid >> 3);  // XCD swizzle (nwg%8==0)
  const int nmn = nwg / NSPLIT;
  const int ksl = bid2 / nmn;
  const int rmn = bid2 - ksl * nmn;
  const int nx = N / BN;
  const int m0 = (rmn / nx) * BM, n0 = (rmn % nx) * BN;
  const int klen = K / NSPLIT;
  const int kbeg = ksl * klen;
  const int wr = w >> 1, wc = w & 1;
  const int lrow = l & 15, lk4 = l >> 4;
  f32x4 acc[MR][NR] = {};

  for (int k0 = kbeg; k0 < kbeg + klen; k0 += BK) {
#pragma unroll
    for (int i = 0; i < AIT; ++i) {
      int idx = t + 256 * i;
      int row = idx >> 3, seg = idx & 7;
      int ss = seg ^ (row & 7);
      cp16(A + (size_t)(m0 + row) * K + k0 + ss * 8, (char*)la + w * 1024 + i * 4096);
    }
#pragma unroll
    for (int i = 0; i < BIT; ++i) {
      int idx = t + 256 * i;
      int row = idx >> 3, seg = idx & 7;
      int ss = seg ^ (row & 7);
      cp16(Bt + (size_t)(n0 + row) * K + k0 + ss * 8, (char*)lb + w * 1024 + i * 4096);
    }
    __syncthreads();
#pragma unroll
    for (int ks = 0; ks < 2; ++ks) {
      bf16x8 af[MR], bfr[NR];
#pragma unroll
      for (int mi = 0; mi < MR; ++mi) {
        int row = wr * (BM / 2) + mi * 16 + lrow;
        int ss = (ks * 4 + lk4) ^ (row & 7);
        af[mi] = *(const bf16x8*)((const char*)la + row * 128 + ss * 16);
      }
#pragma unroll
      for (int ni = 0; ni < NR; ++ni) {
        int row = wc * (BN / 2) + ni * 16 + lrow;
        int ss = (ks * 4 + lk4) ^ (row & 7);
        bfr[ni] = *(const bf16x8*)((const char*)lb + row * 128 + ss * 16);
      }
#pragma unroll
      for (int mi = 0; mi < MR; ++mi)
#pragma unroll
        for (int ni = 0; ni < NR; ++ni)
          acc[mi][ni] = __builtin_amdgcn_mfma_f32_16x16x32_bf16(af[mi], bfr[ni], acc[mi][ni], 0, 0, 0);
    }
    __syncthreads();
  }

#pragma unroll
  for (int mi = 0; mi < MR; ++mi) {
    int rowb = m0 + wr * (BM / 2) + mi * 16 + lk4 * 4;
#pragma unroll
    for (int ni = 0; ni < NR; ++ni) {
      int col = n0 + wc * (BN / 2) + ni * 16 + lrow;
      f32x4 a = acc[mi][ni];
#pragma unroll
      for (int r = 0; r < 4; ++r) {
        size_t off = (size_t)(rowb + r) * N + col;
        if (EPI == 0) {
          ((unsigned short*)Cp)[off] = f2bf(a[r]);
        } else if (EPI == 2) {
          float v = a[r] + bias[col];
          ((unsigned short*)Cp)[off] = f2bf(0.5f * v * (1.0f + erff(v * 0.70710678f)));
        } else if (EPI == 3) {
          ((unsigned short*)Cp)[off] = f2bf(a[r] + bias[col] + ((const float*)resv)[off]);
        } else if (EPI == 4) {
          ((float*)Cp)[off] = a[r] + bias[col] + bf2f(((const unsigned short*)resv)[off]);
        } else {  // EPI == 5: bf16 partial for split-K
          ((unsigned short*)Cp)[(size_t)ksl * M * N + off] = f2bf(a[r]);
        }
      }
    }
  }
}

// ------- split-K(2) combine for MLP2: out = p0 + p1 + b2 + residual(bf16) -------
__global__ __launch_bounds__(256) void mlp2_combine(const unsigned short* __restrict__ p,
                                                    const float* __restrict__ b2,
                                                    const unsigned short* __restrict__ xa,
                                                    float* __restrict__ out) {
  const int row = blockIdx.x, t = threadIdx.x;
  const size_t off = (size_t)row * 1024 + t * 4;
  ushort4_t a = *(const ushort4_t*)(p + off);
  ushort4_t b = *(const ushort4_t*)(p + (size_t)TOKENS * 1024 + off);
  f32x4 bb = *(const f32x4*)(b2 + t * 4);
  ushort4_t xv = *(const ushort4_t*)(xa + off);
  f32x4 o;
#pragma unroll
  for (int j = 0; j < 4; ++j) o[j] = bf2f(a[j]) + bf2f(b[j]) + bb[j] + bf2f(xv[j]);
  *(f32x4*)(out + off) = o;
}

// ---------------- fused flash attention, KV-split x2, single-buffered LDS ----------
__global__ __launch_bounds__(256, 2) void attn4(const unsigned short* __restrict__ qkv,
                                                unsigned short* __restrict__ Op,
                                                float2* __restrict__ ml) {
  __shared__ unsigned short lk_[64 * 64];  // K [key][d], seg^(key&7) swizzled
  __shared__ unsigned short lvt[64 * 64];  // V^T [d][key], kseg^(d&7) swizzled
  const int t = threadIdx.x, wv = t >> 6, l = t & 63;
  const int chunk = blockIdx.x & 1, qb = blockIdx.x >> 1;
  const int h = blockIdx.y, b = blockIdx.z;
  const size_t tok0 = (size_t)b * SEQ;
  const int lq = l & 31, hi = l >> 5, l7 = l & 7;
  const int qrow = qb * 128 + wv * 32 + lq;
  const int kstart = chunk * 16;  // 16 tiles of 64 keys per chunk

  bf16x8 qf[4];
#pragma unroll
  for (int dc = 0; dc < 4; ++dc)
    qf[dc] = *(const bf16x8*)(qkv + (tok0 + qrow) * TOKSTRIDE + h * DHEAD + dc * 16 + hi * 8);

  float mrun = -1e30f, lsum = 0.0f;
  f32x16 o0 = {}, o1 = {};

  {
#pragma unroll
    for (int i = 0; i < 2; ++i) {
      int idx = t + 256 * i;
      int key = idx >> 3, seg = idx & 7;
      cp16(qkv + (tok0 + kstart * 64 + key) * TOKSTRIDE + 1024 + h * DHEAD + ((seg ^ (key & 7)) << 3),
           (char*)lk_ + wv * 1024 + i * 4096);
    }
#pragma unroll
    for (int i = 0; i < 2; ++i) {
      int idx = t + 256 * i;
      int key = idx & 63, seg = idx >> 6;
      ushort8 v8 = *(const ushort8*)(qkv + (tok0 + kstart * 64 + key) * TOKSTRIDE + 2048 + h * DHEAD + seg * 8);
#pragma unroll
      for (int j = 0; j < 8; ++j) {
        int d = seg * 8 + j;
        lvt[d * 64 + (((key >> 3) ^ (d & 7)) << 3) + (key & 7)] = v8[j];
      }
    }
  }
  __syncthreads();

  for (int kb = 0; kb < 16; ++kb) {
    const bool more = (kb + 1 < 16);
    const int kpre = kstart + kb + 1;

    f32x16 s0 = {}, s1 = {};
    __builtin_amdgcn_s_setprio(1);
#pragma unroll
    for (int dc = 0; dc < 4; ++dc) {
      int sgA = (dc * 2 + hi) ^ l7;
      bf16x8 kf0 = *(const bf16x8*)((const char*)lk_ + lq * 128 + (sgA << 4));
      bf16x8 kf1 = *(const bf16x8*)((const char*)lk_ + (32 + lq) * 128 + (sgA << 4));
      s0 = __builtin_amdgcn_mfma_f32_32x32x16_bf16(kf0, qf[dc], s0, 0, 0, 0);
      s1 = __builtin_amdgcn_mfma_f32_32x32x16_bf16(kf1, qf[dc], s1, 0, 0, 0);
    }
    __builtin_amdgcn_s_setprio(0);

    asm volatile("s_waitcnt lgkmcnt(0)" ::: "memory");
    BARR;
    __builtin_amdgcn_sched_barrier(0);

    ushort8 vpre[2];
    if (more) {
#pragma unroll
      for (int i = 0; i < 2; ++i) {
        int idx = t + 256 * i;
        int key = idx >> 3, seg = idx & 7;
        cp16(qkv + (tok0 + kpre * 64 + key) * TOKSTRIDE + 1024 + h * DHEAD + ((seg ^ (key & 7)) << 3),
             (char*)lk_ + wv * 1024 + i * 4096);
      }
#pragma unroll
      for (int i = 0; i < 2; ++i) {
        int idx = t + 256 * i;
        int key = idx & 63, seg = idx >> 6;
        vpre[i] = *(const ushort8*)(qkv + (tok0 + kpre * 64 + key) * TOKSTRIDE + 2048 + h * DHEAD + seg * 8);
      }
    }

    float mx[8];
#pragma unroll
    for (int r = 0; r < 8; ++r)
      mx[r] = fmaxf(fmaxf(s0[r], s0[r + 8]), fmaxf(s1[r], s1[r + 8]));
#pragma unroll
    for (int r = 0; r < 4; ++r) mx[r] = fmaxf(mx[r], mx[r + 4]);
    float m01 = fmaxf(fmaxf(mx[0], mx[1]), fmaxf(mx[2], mx[3]));
    float pm = fmaxf(m01, __shfl_xor(m01, 32));

    if (__any(pm > mrun + 8.0f)) {
      float mn = fmaxf(mrun, pm);
      float alpha = EXP2(mrun - mn);
      mrun = mn;
      lsum *= alpha;
#pragma unroll
      for (int r = 0; r < 16; ++r) {
        int qi = (r & 3) + 8 * (r >> 2) + 4 * hi;
        float ar = __shfl(alpha, qi);
        o0[r] *= ar; o1[r] *= ar;
      }
    }

    float p0[16], p1[16], ts[16];
#pragma unroll
    for (int r = 0; r < 16; ++r) { p0[r] = EXP2(s0[r] - mrun); }
#pragma unroll
    for (int r = 0; r < 16; ++r) { p1[r] = EXP2(s1[r] - mrun); }
#pragma unroll
    for (int r = 0; r < 16; ++r) ts[r] = p0[r] + p1[r];
#pragma unroll
    for (int st = 8; st > 0; st >>= 1)
#pragma unroll
      for (int r = 0; r < 8; ++r)
        if (r < st) ts[r] += ts[r + st];
    float psum = ts[0] + __shfl_xor(ts[0], 32);
    lsum += psum;

    unsigned W0[8], W1[8];
#pragma unroll
    for (int mI = 0; mI < 8; ++mI) {
      W0[mI] = cvt_pk_bf16(p0[2 * mI], p0[2 * mI + 1]);
      W1[mI] = cvt_pk_bf16(p1[2 * mI], p1[2 * mI + 1]);
    }
#if !HAS_PL32
    unsigned X0[8], X1[8];
#pragma unroll
    for (int mI = 0; mI < 8; ++mI) {
      X0[mI] = __shfl_xor((int)W0[mI], 32);
      X1[mI] = __shfl_xor((int)W1[mI], 32);
    }
#endif

    __builtin_amdgcn_s_setprio(1);
#pragma unroll
    for (int kt = 0; kt < 2; ++kt) {
#pragma unroll
      for (int c = 0; c < 2; ++c) {
        u32x4 fw;
#if HAS_PL32
        unsigned a0 = (kt == 0) ? W0[4 * c + 0] : W1[4 * c + 0];
        unsigned a1 = (kt == 0) ? W0[4 * c + 1] : W1[4 * c + 1];
        unsigned b0 = (kt == 0) ? W0[4 * c + 2] : W1[4 * c + 2];
        unsigned b1 = (kt == 0) ? W0[4 * c + 3] : W1[4 * c + 3];
        u32x2 pa = __builtin_amdgcn_permlane32_swap(a0, b0, false, false);
        u32x2 pb = __builtin_amdgcn_permlane32_swap(a1, b1, false, false);
        fw[0] = pa[0]; fw[1] = pb[0]; fw[2] = pa[1]; fw[3] = pb[1];
#else
        if (kt == 0) {
          fw[0] = hi ? X0[4 * c + 2] : W0[4 * c + 0];
          fw[1] = hi ? X0[4 * c + 3] : W0[4 * c + 1];
          fw[2] = hi ? W0[4 * c + 2] : X0[4 * c + 0];
          fw[3] = hi ? W0[4 * c + 3] : X0[4 * c + 1];
        } else {
          fw[0] = hi ? X1[4 * c + 2] : W1[4 * c + 0];
          fw[1] = hi ? X1[4 * c + 3] : W1[4 * c + 1];
          fw[2] = hi ? W1[4 * c + 2] : X1[4 * c + 0];
          fw[3] = hi ? W1[4 * c + 3] : X1[4 * c + 1];
        }
#endif
        bf16x8 pf = __builtin_bit_cast(bf16x8, fw);
        int ksg = (kt * 4 + c * 2 + hi) ^ l7;
        bf16x8 vfA = *(const bf16x8*)((const char*)lvt + lq * 128 + (ksg << 4));
        bf16x8 vfB = *(const bf16x8*)((const char*)lvt + (32 + lq) * 128 + (ksg << 4));
        o0 = __builtin_amdgcn_mfma_f32_32x32x16_bf16(pf, vfA, o0, 0, 0, 0);
        o1 = __builtin_amdgcn_mfma_f32_32x32x16_bf16(pf, vfB, o1, 0, 0, 0);
      }
    }
    __builtin_amdgcn_s_setprio(0);

    asm volatile("s_waitcnt lgkmcnt(0)" ::: "memory");
    BARR;
    __builtin_amdgcn_sched_barrier(0);

    if (more) {
#pragma unroll
      for (int i = 0; i < 2; ++i) {
        int idx = t + 256 * i;
        int key = idx & 63, seg = idx >> 6;
#pragma unroll
        for (int j = 0; j < 8; ++j) {
          int d = seg * 8 + j;
          lvt[d * 64 + (((key >> 3) ^ (d & 7)) << 3) + (key & 7)] = vpre[i][j];
        }
      }
    }
    asm volatile("s_waitcnt vmcnt(0) lgkmcnt(0)" ::: "memory");
    BARR;
    __builtin_amdgcn_sched_barrier(0);
  }

  const size_t cbase = (size_t)chunk * TOKENS;
#pragma unroll
  for (int r = 0; r < 16; ++r) {
    int qi = (r & 3) + 8 * (r >> 2) + 4 * hi;
    size_t rowoff = (cbase + tok0 + qb * 128 + wv * 32 + qi) * (size_t)1024 + h * DHEAD;
    Op[rowoff + lq]      = f2bf(o0[r]);
    Op[rowoff + 32 + lq] = f2bf(o1[r]);
  }
  if (l < 32) {
    size_t tokr = tok0 + qb * 128 + wv * 32 + lq;
    ml[(cbase + tokr) * 16 + h] = make_float2(mrun, lsum);
  }
}

// ---------------- combine the 2 KV-chunk partials -> bf16 attno ----------------
__global__ __launch_bounds__(256) void attn_combine2(const unsigned short* __restrict__ Op,
                                                     const float2* __restrict__ ml,
                                                     unsigned short* __restrict__ out) {
  const int t = threadIdx.x, w = t >> 6, l = t & 63;
  const size_t tok = blockIdx.x * 4 + w;
#pragma unroll
  for (int h = 0; h < 16; ++h) {
    float2 a = ml[tok * 16 + h];
    float2 c = ml[((size_t)TOKENS + tok) * 16 + h];
    float M = fmaxf(a.x, c.x);
    float w0 = EXP2(a.x - M), w1 = EXP2(c.x - M);
    float inv = 1.0f / (a.y * w0 + c.y * w1);
    int col = h * 64 + l;
    float o = (bf2f(Op[tok * 1024 + col]) * w0 +
               bf2f(Op[((size_t)TOKENS + tok) * 1024 + col]) * w1) * inv;
    out[tok * 1024 + col] = f2bf(o);
  }
}

extern "C" void kernel_launch(void* const* d_in, const int* in_sizes, int n_in,
                              void* d_out, int out_size, void* d_ws, size_t ws_size,
                              hipStream_t stream) {
  const float* x    = (const float*)d_in[0];
  const float* ln1g = (const float*)d_in[1];
  const float* ln1b = (const float*)d_in[2];
  const float* wqkv = (const float*)d_in[3];
  const float* wout = (const float*)d_in[4];
  const float* bout = (const float*)d_in[5];
  const float* ln2g = (const float*)d_in[6];
  const float* ln2b = (const float*)d_in[7];
  const float* w1   = (const float*)d_in[8];
  const float* b1   = (const float*)d_in[9];
  const float* w2   = (const float*)d_in[10];
  const float* b2   = (const float*)d_in[11];

  char* ws = (char*)d_ws;
  unsigned short* wqkvT = (unsigned short*)ws; ws += (size_t)3072 * 1024 * 2;
  unsigned short* woutT = (unsigned short*)ws; ws += (size_t)1024 * 1024 * 2;
  unsigned short* w1T   = (unsigned short*)ws; ws += (size_t)4096 * 1024 * 2;
  unsigned short* w2T   = (unsigned short*)ws; ws += (size_t)1024 * 4096 * 2;
  unsigned short* h1    = (unsigned short*)ws; ws += (size_t)TOKENS * 1024 * 2;
  unsigned short* qkvb  = (unsigned short*)ws; ws += (size_t)TOKENS * 3072 * 2;
  unsigned short* attno = (unsigned short*)ws; ws += (size_t)TOKENS * 1024 * 2;
  unsigned short* xa    = (unsigned short*)ws; ws += (size_t)TOKENS * 1024 * 4;  // bf16 (slot fp32-sized)
  unsigned short* h2    = (unsigned short*)ws; ws += (size_t)TOKENS * 1024 * 2;
  unsigned short* hid   = (unsigned short*)ws; ws += (size_t)TOKENS * 4096 * 2;
  float2*         mlbuf = (float2*)ws;         ws += (size_t)2 * TOKENS * 16 * 8;
  unsigned short* Opart = hid;  // alias: 2x bf16 partials = 16MB in hid, dead until MLP1
  unsigned short* mlp2p = h1;   // alias: 2x bf16 partials = 16MB in h1+qkvb; dead after attn4

  // prep: weight transposes (W_q pre-scaled by 0.125*log2e) + LN1, one launch
  prep_all<<<12288 + TOKENS, 256, 0, stream>>>(wqkv, wout, w1, w2, wqkvT, woutT, w1T, w2T,
                                               x, ln1g, ln1b, h1);
  // minw=3 on BN=128 GEMMs: acc64+frags32+addr~20 = ~116 VGPR < 170 cap (no spill)
  gemm_bt<0, 128, 3, 1><<<768, 256, 0, stream>>>(h1, wqkvT, qkvb, nullptr, nullptr, TOKENS, 3072, 1024);
  attn4<<<dim3(2 * SEQ / 128, HEADS, BATCH), 256, 0, stream>>>(qkvb, Opart, mlbuf);
  attn_combine2<<<TOKENS / 4, 256, 0, stream>>>(Opart, mlbuf, attno);
  gemm_bt<3, 64, 3, 1><<<512, 256, 0, stream>>>(attno, woutT, xa, bout, x, TOKENS, 1024, 1024);
  ln_rows_bf<<<TOKENS, 256, 0, stream>>>(xa, ln2g, ln2b, h2);
  gemm_bt<2, 128, 3, 1><<<1024, 256, 0, stream>>>(h2, w1T, hid, b1, nullptr, TOKENS, 4096, 1024);
  // MLP2 split-K x2, BN=128, bf16 partials
  gemm_bt<5, 128, 3, 2><<<512, 256, 0, stream>>>(hid, w2T, mlp2p, nullptr, nullptr, TOKENS, 1024, 4096);
  mlp2_combine<<<TOKENS, 256, 0, stream>>>(mlp2p, b2, xa, (float*)d_out);
}